// Round 7
// baseline (930.425 us; speedup 1.0000x reference)
//
#include <hip/hip_runtime.h>
#include <math.h>

// CV-photonic circuit: WIRES=4, LAYERS=2, CUTOFF=10, BATCH=2048.
// R20 = R18 (best, 681us: 2 batch-states v4f LDS, hoisted ds_read_b128,
//  dwordx4 matrix loads, elementwise_fma — NO asm, it lost twice) +
//  (1) 2 FIBERS per thread: 512-thread blocks, thread t handles fibers
//      t and t+500 (digit d0+5). Per pass per wave: 2x work against the
//      same barrier/latency overhead (the only lever that has won: R14's
//      2-states, R18's hoisting). waves_per_eu(2) -> 256 VGPR budget.
//  (2) Bank-conflict digit swaps: wave64 b128 is conflict-free iff the
//      lane-fastest digit stride mod 8 is odd {1,101}; W(0,3)/WU(3)/BS(3,0)
//      had stride-10 fastest (2-way conflict) -> swap (qa,qb) so the
//      101-stride axis is fastest. (W(1,3) unfixable this way; left as-is.)

namespace {

constexpr int NTB = 512;                  // threads per state block (8 waves)
constexpr int SMEM_STATE = 162352;        // 161584 state + 640 uv + 128 red
constexpr double THETA = 0.7853981633974483096; // pi/4

struct cxf { float x, y; };
typedef float v2f __attribute__((ext_vector_type(2)));
typedef float v4f __attribute__((ext_vector_type(4)));

// ws float layout:
// [0,100)       V    (V[k*10+m]; used directly for the V^T gate)
// [100,200)     VT   (VT[k*10+i] = V[i][k]; used for the V gate)
// [200,1200)    Wt   (10 real 10x10, transposed: Wt[n*100+k*10+i]=W_n[i][k])
// [1200,5000)   BSt  cxf[19*100] zero-padded, transposed
// [5000,6600)   ULt  cxf[8*100]: f=0 (L0 UL0, VT-folded), f=4,5,6 (measure)
// [6600,9800)   stage cxf[16*100] raw S_lay (0..7) / D_lay (8..15)
// [9800,15800)  WUt  cxf[30*100]: WU_{b}[n] transposed, id=(b-1)*10+n
// [15872,...)   u    cxf[B*4*10] encoded per-(b,w) vectors
constexpr int U_OFF = 15872;

__device__ __forceinline__ cxf gen_squeeze_f(int i, int j, float zr, float zi){
  if (j == i+2){ float g = 0.5f*sqrtf((float)((i+1)*(i+2))); return {zr*g, -zi*g}; }
  if (i == j+2){ float g = 0.5f*sqrtf((float)((j+1)*(j+2))); return {-zr*g, -zi*g}; }
  return {0.f, 0.f};
}
__device__ __forceinline__ cxf gen_disp_f(int i, int j, float ar, float ai){
  if (i == j+1){ float g = sqrtf((float)i); return {ar*g, ai*g}; }
  if (j == i+1){ float g = sqrtf((float)j); return {-ar*g, ai*g}; }
  return {0.f, 0.f};
}

// Wave-cooperative fixed-schedule fp32 expm: result = exp(M), n x n (n<=10).
__device__ void expm_f32(bool act, int n, cxf* M, cxf* P, cxf* T, cxf* R, int lane){
  const int n2 = n*n;
  if (act){
    for (int e=lane; e<n2; e+=64){ M[e].x *= 0x1p-10f; M[e].y *= 0x1p-10f; }
    for (int e=lane; e<n2; e+=64){
      P[e] = M[e];
      cxf r = M[e];
      if (e % (n+1) == 0) r.x += 1.f;
      R[e] = r;
    }
  }
  __syncthreads();
  for (int t=2; t<=12; ++t){
    if (act){
      float inv = 1.f/(float)t;
      for (int e=lane; e<n2; e+=64){
        int i = e/n, j = e - i*n;
        float ax=0.f, ay=0.f;
        for (int k=0;k<n;k++){
          cxf p = P[i*n+k], m = M[k*n+j];
          ax += p.x*m.x - p.y*m.y;
          ay += p.x*m.y + p.y*m.x;
        }
        T[e] = {ax*inv, ay*inv};
      }
    }
    __syncthreads();
    { cxf* tmp = P; P = T; T = tmp; }
    if (act){ for (int e=lane; e<n2; e+=64){ R[e].x += P[e].x; R[e].y += P[e].y; } }
    __syncthreads();
  }
  for (int s=0; s<10; ++s){
    if (act){
      for (int e=lane; e<n2; e+=64){
        int i = e/n, j = e - i*n;
        float ax=0.f, ay=0.f;
        for (int k=0;k<n;k++){
          cxf p = R[i*n+k], q = R[k*n+j];
          ax += p.x*q.x - p.y*q.y;
          ay += p.x*q.y + p.y*q.x;
        }
        T[e] = {ax, ay};
      }
    }
    __syncthreads();
    { cxf* tmp = R; R = T; T = tmp; }
    __syncthreads();
  }
}

// ------------- Kernel A: 45 expm tasks fully parallel over 12 blocks -------
__global__ __launch_bounds__(256)
void gates_kernel(const float* __restrict__ dmag, const float* __restrict__ dphase,
                  const float* __restrict__ smag, const float* __restrict__ sphase,
                  float* __restrict__ wsf){
  __shared__ double lam[10];
  __shared__ float scr[4][4][200];      // [wave][buf] cxf[100]
  const int tid = threadIdx.x;
  const int wv = tid >> 6, lane = tid & 63, g = blockIdx.x;
  float* ws_V  = wsf;
  float* ws_VT = wsf + 100;
  float* ws_W  = wsf + 200;
  cxf* ws_BS   = (cxf*)(wsf + 1200);
  cxf* ws_stage= (cxf*)(wsf + 6600);

  if (tid < 10){
    double lo = -6.0, hi = 6.0;
    for (int it=0; it<80; ++it){
      double mid = 0.5*(lo+hi);
      int cnt = 0; double q = 1.0;
      for (int i=0;i<10;i++){
        q = -mid - (i ? (double)i/q : 0.0);
        if (fabs(q) < 1e-300) q = -1e-300;
        if (q < 0.0) cnt++;
      }
      if (cnt > tid) hi = mid; else lo = mid;
    }
    double x = 0.5*(lo+hi);
    double p[10];
    p[0] = 1.0; p[1] = x;
    for (int k=1;k<9;k++) p[k+1] = (x*p[k] - sqrt((double)k)*p[k-1]) * (1.0/sqrt((double)(k+1)));
    double nn=0.0; for (int k=0;k<10;k++) nn += p[k]*p[k];
    double inv = 1.0/sqrt(nn);
    lam[tid] = x;
    if (g == 0){
      for (int k=0;k<10;k++){
        float v = (float)(p[k]*inv);
        ws_V[k*10+tid]  = v;
        ws_VT[tid*10+k] = v;
      }
    }
  }
  __syncthreads();

  int t = g*4 + wv;
  bool act = (t < 45);
  int n = 10, bn = 0, ilo = 0;
  if (act && t >= 10 && t < 29){
    bn = t - 10; ilo = bn < 10 ? 0 : bn - 9;
    int ihi = bn < 10 ? bn : 9;
    n = ihi - ilo + 1;
  }
  cxf* M = (cxf*)scr[wv][0];
  cxf* P = (cxf*)scr[wv][1];
  cxf* T = (cxf*)scr[wv][2];
  cxf* R = (cxf*)scr[wv][3];
  if (act){
    if (t < 10){
      float l = (float)lam[t];   // Q = -0.5*(a - ad)
      for (int e=lane; e<100; e+=64){
        int i=e/10, j=e-10*i;
        float v = 0.f;
        if (j == i+1) v = -0.5f*l*sqrtf((float)(i+1));
        else if (i == j+1) v = 0.5f*l*sqrtf((float)i);
        M[e] = {v, 0.f};
      }
    } else if (t < 29){
      for (int e=lane; e<n*n; e+=64){
        int rr=e/n, c=e-n*rr;
        float v = 0.f;
        if (c == rr+1) v = (float)THETA*sqrtf((float)((ilo+rr+1)*(bn-ilo-rr)));
        else if (rr == c+1) v = (float)THETA*sqrtf((float)((ilo+c+1)*(bn-ilo-c)));
        M[e] = {0.f, v};
      }
    } else {
      int idx = t-29, kind = idx>>3, L=(idx>>2)&1, w=idx&3;
      float r_ = kind ? dmag[L*4+w]   : smag[L*4+w];
      float ph = kind ? dphase[L*4+w] : sphase[L*4+w];
      float zr = r_*cosf(ph), zi = r_*sinf(ph);
      for (int e=lane; e<100; e+=64){
        int i=e/10, j=e-10*i;
        M[e] = kind ? gen_disp_f(i,j,zr,zi) : gen_squeeze_f(i,j,zr,zi);
      }
    }
  }
  __syncthreads();
  expm_f32(act, n, M, P, T, R, lane);
  if (act){
    if (t < 10){
      for (int e=lane;e<100;e+=64){
        int i=e/10, j=e-10*i;
        ws_W[t*100 + j*10 + i] = R[e].x;   // transposed, real
      }
    } else if (t < 29){
      for (int e=lane;e<100;e+=64){
        int rr=e/10, c=e-10*rr;
        cxf o; o.x=0.f; o.y=0.f;
        if (rr < n && c < n) o = R[rr*n+c];
        ws_BS[bn*100 + c*10 + rr] = o;     // zero-padded + transposed
      }
    } else {
      int idx = t-29;
      for (int e=lane;e<100;e+=64) ws_stage[idx*100 + e] = R[e];
    }
  }
}

// ---- Kernel A2: UL products, VT fold, and WU_b[n] = W_n * UL_b fusion -----
__global__ __launch_bounds__(512)
void fuse_kernel(float* __restrict__ wsf){
  __shared__ cxf ulraw[8][100];          // raw UL[f] = D*S, [i*10+j]
  const int tid = threadIdx.x, wv = tid>>6, lane = tid&63;
  const cxf* stage = (const cxf*)(wsf + 6600);
  cxf* ws_UL = (cxf*)(wsf + 5000);
  cxf* ws_WU = (cxf*)(wsf + 9800);
  const float* V  = wsf;
  const float* Wt = wsf + 200;
  const cxf* Sm = stage + wv*100;
  const cxf* Dm = stage + (8+wv)*100;
  for (int e=lane; e<100; e+=64){
    int i=e/10, j=e-10*i;
    float ax=0.f, ay=0.f;
    for (int k=0;k<10;k++){
      cxf d=Dm[i*10+k], s=Sm[k*10+j];
      ax += d.x*s.x - d.y*s.y;
      ay += d.x*s.y + d.y*s.x;
    }
    ulraw[wv][e] = {ax, ay};
  }
  __syncthreads();
  // f=0 only: UL0 <- V^T * UL0 (carries L1's V0^T). Two elems per lane.
  cxf t0={0.f,0.f}, t1={0.f,0.f};
  if (wv == 0){
    {
      int e=lane, i=e/10, j=e-10*i;
      float ox=0.f, oy=0.f;
      for (int k=0;k<10;k++){ float v=V[k*10+i]; ox+=v*ulraw[0][k*10+j].x; oy+=v*ulraw[0][k*10+j].y; }
      t0 = {ox, oy};
    }
    if (lane+64 < 100){
      int e=lane+64, i=e/10, j=e-10*i;
      float ox=0.f, oy=0.f;
      for (int k=0;k<10;k++){ float v=V[k*10+i]; ox+=v*ulraw[0][k*10+j].x; oy+=v*ulraw[0][k*10+j].y; }
      t1 = {ox, oy};
    }
  }
  __syncthreads();
  if (wv == 0){
    ulraw[0][lane] = t0;
    if (lane+64 < 100) ulraw[0][lane+64] = t1;
  }
  __syncthreads();
  // Export ULt (transposed) for f in {0,4,5,6}
  for (int e=tid; e<400; e+=512){
    int fi = e/100, r = e-100*fi;
    int f = (fi==0) ? 0 : (3+fi);        // 0,4,5,6
    int i=r/10, j=r-10*i;
    ws_UL[f*100 + j*10 + i] = ulraw[f][i*10+j];
  }
  // Phase 2: WU_b[n] = W_n * ulraw[b], id=(b-1)*10+n, 30 tasks over 8 waves.
  for (int round=0; round<4; ++round){
    int id = round*8 + wv;
    if (id < 30){
      int b = 1 + id/10, n = id - (id/10)*10;
      const cxf* Ub = ulraw[b];
      for (int e=lane; e<100; e+=64){
        int i=e/10, j=e-10*i;
        float ax=0.f, ay=0.f;
        for (int k=0;k<10;k++){
          float w = Wt[n*100 + k*10 + i];   // W_n[i][k]
          ax += w*Ub[k*10+j].x;
          ay += w*Ub[k*10+j].y;
        }
        cxf o; o.x=ax; o.y=ay;
        ws_WU[id*100 + j*10 + i] = o;       // transposed
      }
    }
  }
}

// ------------- Kernel B: per-(b,w) encoding vector u = D*(S*e0), fp32 ------
__global__ __launch_bounds__(128)
void enc_kernel(const float* __restrict__ jets, const float* __restrict__ sscale,
                float* __restrict__ wsf){
  __shared__ float scr[2][4][200];
  __shared__ cxf col[10];
  __shared__ cxf uacc[10];
  const int tid = threadIdx.x, wv = tid>>6, lane = tid&63;
  const int blk = blockIdx.x, b = blk>>2, w = blk&3;

  float eta = jets[b*12 + w*3 + 0];
  float jph = jets[b*12 + w*3 + 1];
  float pt  = jets[b*12 + w*3 + 2];

  cxf* M = (cxf*)scr[wv][0];
  cxf* P = (cxf*)scr[wv][1];
  cxf* T = (cxf*)scr[wv][2];
  cxf* R = (cxf*)scr[wv][3];
  {
    float zr, zi;
    if (wv == 0){ float phs = pt*jph*0.5f; zr = eta*cosf(phs); zi = eta*sinf(phs); }
    else {
      double sc = 10.0/(1.0 + exp(-(double)sscale[0])) + 0.01;
      float mag = (float)sc*pt; zr = mag*cosf(eta); zi = mag*sinf(eta);
    }
    for (int e=lane; e<100; e+=64){
      int i=e/10, j=e-10*i;
      M[e] = wv ? gen_disp_f(i,j,zr,zi) : gen_squeeze_f(i,j,zr,zi);
    }
  }
  __syncthreads();
  expm_f32(true, 10, M, P, T, R, lane);
  cxf* Rs = (cxf*)scr[0][3];
  cxf* Rd = (cxf*)scr[1][3];
  if (tid < 10) col[tid] = Rs[tid*10];           // squeeze column 0
  __syncthreads();
  if (tid < 10){
    float ax=0.f, ay=0.f;
    for (int k=0;k<10;k++){
      cxf d = Rd[tid*10+k], c = col[k];
      ax += d.x*c.x - d.y*c.y;
      ay += d.x*c.y + d.y*c.x;
    }
    uacc[tid] = {ax, ay};
  }
  __syncthreads();
  if (tid < 10){
    float rx, ry;
    if (w == 0){
      rx = 0.f; ry = 0.f;
      for (int k=0;k<10;k++){
        float v = wsf[k*10 + tid];               // (V^T)[tid][k]
        rx += v*uacc[k].x;
        ry += v*uacc[k].y;
      }
    } else { rx = uacc[tid].x; ry = uacc[tid].y; }
    float* u_out = wsf + U_OFF + (b*40 + w*10 + tid)*2;
    u_out[0] = rx;
    u_out[1] = ry;
  }
}

// ---------------- Kernel C: the circuit, 2 states x 2 fibers ---------------
// Padded digit strides: element (c0,c1,c2,c3) -> c0*1010 + c1*101 + c2*10 + c3.
__device__ __forceinline__ constexpr int WS(int w){
  return w==0 ? 1010 : (w==1 ? 101 : (w==2 ? 10 : 1));
}

#define SHUF4(v) __builtin_shufflevector(v, v, 1, 0, 3, 2)

#define DECL_A \
  v4f a0={0.f,0.f,0.f,0.f}, a1=a0, a2=a0, a3=a0, a4=a0, a5=a0, a6=a0, a7=a0, a8=a0, a9=a0;
#define DECL_B \
  v4f b0={0.f,0.f,0.f,0.f}, b1=b0, b2=b0, b3=b0, b4=b0, b5=b0, b6=b0, b7=b0, b8=b0, b9=b0;

#define CE_A(i,ur,ui) \
  a##i = __builtin_elementwise_fma((v4f){(ur),(ur),(ur),(ur)}, vv, a##i); \
  a##i = __builtin_elementwise_fma((v4f){-(ui),(ui),-(ui),(ui)}, vs, a##i);
#define CE_B(i,ur,ui) \
  b##i = __builtin_elementwise_fma((v4f){(ur),(ur),(ur),(ur)}, vv, b##i); \
  b##i = __builtin_elementwise_fma((v4f){-(ui),(ui),-(ui),(ui)}, vs, b##i);
#define RE_A(i,u) a##i = __builtin_elementwise_fma((v4f){(u),(u),(u),(u)}, vv, a##i);
#define RE_B(i,u) b##i = __builtin_elementwise_fma((v4f){(u),(u),(u),(u)}, vv, b##i);

#define CROW_A CE_A(0,q0.x,q0.y) CE_A(1,q0.z,q0.w) CE_A(2,q1.x,q1.y) CE_A(3,q1.z,q1.w) \
  CE_A(4,q2.x,q2.y) CE_A(5,q2.z,q2.w) CE_A(6,q3.x,q3.y) CE_A(7,q3.z,q3.w) \
  CE_A(8,q4.x,q4.y) CE_A(9,q4.z,q4.w)
#define CROW_B CE_B(0,q0.x,q0.y) CE_B(1,q0.z,q0.w) CE_B(2,q1.x,q1.y) CE_B(3,q1.z,q1.w) \
  CE_B(4,q2.x,q2.y) CE_B(5,q2.z,q2.w) CE_B(6,q3.x,q3.y) CE_B(7,q3.z,q3.w) \
  CE_B(8,q4.x,q4.y) CE_B(9,q4.z,q4.w)

#define RROWS_A(ra_,rb_) \
  { { v4f vv=ra_; RE_A(0,q0.x) RE_A(1,q0.y) RE_A(2,q0.z) RE_A(3,q0.w) RE_A(4,q1.x) \
                  RE_A(5,q1.y) RE_A(6,q1.z) RE_A(7,q1.w) RE_A(8,q2.x) RE_A(9,q2.y) } \
    { v4f vv=rb_; RE_A(0,q2.z) RE_A(1,q2.w) RE_A(2,q3.x) RE_A(3,q3.y) RE_A(4,q3.z) \
                  RE_A(5,q3.w) RE_A(6,q4.x) RE_A(7,q4.y) RE_A(8,q4.z) RE_A(9,q4.w) } }
#define RROWS_B(ga_,gb_) \
  { { v4f vv=ga_; RE_B(0,q0.x) RE_B(1,q0.y) RE_B(2,q0.z) RE_B(3,q0.w) RE_B(4,q1.x) \
                  RE_B(5,q1.y) RE_B(6,q1.z) RE_B(7,q1.w) RE_B(8,q2.x) RE_B(9,q2.y) } \
    { v4f vv=gb_; RE_B(0,q2.z) RE_B(1,q2.w) RE_B(2,q3.x) RE_B(3,q3.y) RE_B(4,q3.z) \
                  RE_B(5,q3.w) RE_B(6,q4.x) RE_B(7,q4.y) RE_B(8,q4.z) RE_B(9,q4.w) } }

// Uniform complex step: one matrix row feeds both fibers.
#define CSTEP2U(rk,gk,krow) { \
  const v4f* Up = (const v4f*)(U + (krow)*10); \
  v4f q0=Up[0],q1=Up[1],q2=Up[2],q3=Up[3],q4=Up[4]; \
  { v4f vv=rk, vs=SHUF4(rk); CROW_A } \
  { v4f vv=gk, vs=SHUF4(gk); CROW_B } }
#define CALL2U CSTEP2U(r0,g0,0) CSTEP2U(r1,g1,1) CSTEP2U(r2,g2,2) CSTEP2U(r3,g3,3) \
  CSTEP2U(r4,g4,4) CSTEP2U(r5,g5,5) CSTEP2U(r6,g6,6) CSTEP2U(r7,g7,7) \
  CSTEP2U(r8,g8,8) CSTEP2U(r9,g9,9)

// Conditional complex steps (two matrices), interleaved per k.
#define CSTEP1A(rk,krow) { \
  const v4f* Up = (const v4f*)(U1 + (krow)*10); \
  v4f q0=Up[0],q1=Up[1],q2=Up[2],q3=Up[3],q4=Up[4]; \
  v4f vv=rk, vs=SHUF4(rk); CROW_A }
#define CSTEP1B(gk,krow) { \
  const v4f* Up = (const v4f*)(U2 + (krow)*10); \
  v4f q0=Up[0],q1=Up[1],q2=Up[2],q3=Up[3],q4=Up[4]; \
  v4f vv=gk, vs=SHUF4(gk); CROW_B }
#define CALL_COND CSTEP1A(r0,0) CSTEP1B(g0,0) CSTEP1A(r1,1) CSTEP1B(g1,1) \
  CSTEP1A(r2,2) CSTEP1B(g2,2) CSTEP1A(r3,3) CSTEP1B(g3,3) \
  CSTEP1A(r4,4) CSTEP1B(g4,4) CSTEP1A(r5,5) CSTEP1B(g5,5) \
  CSTEP1A(r6,6) CSTEP1B(g6,6) CSTEP1A(r7,7) CSTEP1B(g7,7) \
  CSTEP1A(r8,8) CSTEP1B(g8,8) CSTEP1A(r9,9) CSTEP1B(g9,9)

// Uniform real: rows k,k+1 (5 quads) feed both fibers.
#define RSTEP2U(rka,rkb,gka,gkb,krow) { \
  const v4f* Mp = (const v4f*)(Mt + (krow)*10); \
  v4f q0=Mp[0],q1=Mp[1],q2=Mp[2],q3=Mp[3],q4=Mp[4]; \
  RROWS_A(rka,rkb) RROWS_B(gka,gkb) }
#define RALL_U RSTEP2U(r0,r1,g0,g1,0) RSTEP2U(r2,r3,g2,g3,2) RSTEP2U(r4,r5,g4,g5,4) \
  RSTEP2U(r6,r7,g6,g7,6) RSTEP2U(r8,r9,g8,g9,8)

// Conditional real (two matrices), interleaved.
#define RSTEP2A(rka,rkb,krow) { \
  const v4f* Mp = (const v4f*)(Mt1 + (krow)*10); \
  v4f q0=Mp[0],q1=Mp[1],q2=Mp[2],q3=Mp[3],q4=Mp[4]; \
  RROWS_A(rka,rkb) }
#define RSTEP2B(gka,gkb,krow) { \
  const v4f* Mp = (const v4f*)(Mt2 + (krow)*10); \
  v4f q0=Mp[0],q1=Mp[1],q2=Mp[2],q3=Mp[3],q4=Mp[4]; \
  RROWS_B(gka,gkb) }
#define RALL_COND RSTEP2A(r0,r1,0) RSTEP2B(g0,g1,0) RSTEP2A(r2,r3,2) RSTEP2B(g2,g3,2) \
  RSTEP2A(r4,r5,4) RSTEP2B(g4,g5,4) RSTEP2A(r6,r7,6) RSTEP2B(g6,g7,6) \
  RSTEP2A(r8,r9,8) RSTEP2B(g8,g9,8)

#define RD_A v4f r0=S[base1], r1=S[base1+sm], r2=S[base1+2*sm], r3=S[base1+3*sm], \
  r4=S[base1+4*sm], r5=S[base1+5*sm], r6=S[base1+6*sm], r7=S[base1+7*sm], \
  r8=S[base1+8*sm], r9=S[base1+9*sm];
#define RD_B v4f g0=S[base2], g1=S[base2+sm], g2=S[base2+2*sm], g3=S[base2+3*sm], \
  g4=S[base2+4*sm], g5=S[base2+5*sm], g6=S[base2+6*sm], g7=S[base2+7*sm], \
  g8=S[base2+8*sm], g9=S[base2+9*sm];

#define ST_A { S[base1]=a0; S[base1+sm]=a1; S[base1+2*sm]=a2; S[base1+3*sm]=a3; \
  S[base1+4*sm]=a4; S[base1+5*sm]=a5; S[base1+6*sm]=a6; S[base1+7*sm]=a7; \
  S[base1+8*sm]=a8; S[base1+9*sm]=a9; }
#define ST_B { S[base2]=b0; S[base2+sm]=b1; S[base2+2*sm]=b2; S[base2+3*sm]=b3; \
  S[base2+4*sm]=b4; S[base2+5*sm]=b5; S[base2+6*sm]=b6; S[base2+7*sm]=b7; \
  S[base2+8*sm]=b8; S[base2+9*sm]=b9; }

// Uniform complex gate (UL0): fibers t and t+500.
__device__ __forceinline__ void apply1_c4(v4f* S, const cxf* __restrict__ U, int m, int tid){
  const int sm = WS(m);
  const int x0 = (m==0)?1:0, x1=(m<=1)?2:1, x2=(m<=2)?3:2;
  const int s0 = WS(x0), s1 = WS(x1), s2 = WS(x2);
  if (tid < 500){
    int c0=tid/100, rem=tid-100*c0, c1=rem/10, c2=rem-10*c1;
    int base1 = c0*s0 + c1*s1 + c2*s2;
    int base2 = base1 + 5*s0;
    RD_A RD_B
    DECL_A DECL_B
    CALL2U
    ST_A ST_B
  }
}

// Uniform real gate (V / V^T).
__device__ __forceinline__ void apply1_r4(v4f* S, const float* __restrict__ Mt, int m, int tid){
  const int sm = WS(m);
  const int x0 = (m==0)?1:0, x1=(m<=1)?2:1, x2=(m<=2)?3:2;
  const int s0 = WS(x0), s1 = WS(x1), s2 = WS(x2);
  if (tid < 500){
    int c0=tid/100, rem=tid-100*c0, c1=rem/10, c2=rem-10*c1;
    int base1 = c0*s0 + c1*s1 + c2*s2;
    int base2 = base1 + 5*s0;
    RD_A RD_B
    DECL_A DECL_B
    RALL_U
    ST_A ST_B
  }
}

// Real conditional gate W(m1,m2): matrices W_n, W_{n+5}.
__device__ __forceinline__ void applyW4(v4f* S, const float* __restrict__ Wall, int m1, int m2, int tid){
  const int sm  = WS(m2);
  const int sm1 = WS(m1);
  int ra=-1, rb=-1;
  for (int q=0;q<4;q++) if (q!=m1 && q!=m2){ if (ra<0) ra=q; else rb=q; }
  const int sa0 = WS(ra), sb0 = WS(rb);
  const bool sw = (sa0==101 && sb0==10);   // make 101-stride lane-fastest
  const int sa = sw ? sb0 : sa0, sb = sw ? sa0 : sb0;
  if (tid < 500){
    int n = tid/100, rem = tid-100*n, qa = rem/10, qb = rem-10*qa;
    int base1 = n*sm1 + qa*sa + qb*sb;
    int base2 = base1 + 5*sm1;
    const float* __restrict__ Mt1 = Wall + n*100;
    const float* __restrict__ Mt2 = Wall + (n+5)*100;
    RD_A RD_B
    DECL_A DECL_B
    RALL_COND
    ST_A ST_B
  }
}

// Complex conditional gate on m2 selected by c0: WU_b[n] = W_n*UL_b.
__device__ __forceinline__ void applyWU4(v4f* S, const cxf* __restrict__ WUall, int m2, int tid){
  const int sm = WS(m2);
  const int ra = (m2==1)?2:1;
  const int rb = (m2==3)?2:3;
  const int sa0 = WS(ra), sb0 = WS(rb);
  const bool sw = (sa0==101 && sb0==10);
  const int sa = sw ? sb0 : sa0, sb = sw ? sa0 : sb0;
  if (tid < 500){
    int n = tid/100, rem = tid-100*n, qa = rem/10, qb = rem-10*qa;
    int base1 = n*WS(0) + qa*sa + qb*sb;
    int base2 = base1 + 5*WS(0);
    const cxf* __restrict__ U1 = WUall + n*100;
    const cxf* __restrict__ U2 = WUall + (n+5)*100;
    RD_A RD_B
    DECL_A DECL_B
    CALL_COND
    ST_A ST_B
  }
}

// Read-only measure: both fibers, both states.
__device__ __forceinline__ v2f measure14(const v4f* S, const cxf* __restrict__ U, int m, int tid){
  const int sm = WS(m);
  const int x0 = (m==0)?1:0, x1=(m<=1)?2:1, x2=3;
  const int s0 = WS(x0), s1 = WS(x1), s2 = WS(x2);
  v2f s = {0.f, 0.f};
  if (tid < 500){
    int c0=tid/100, rem=tid-100*c0, c1=rem/10, c2=rem-10*c1;
    int base1 = c0*s0 + c1*s1 + c2*s2;
    int base2 = base1 + 5*s0;
    RD_A RD_B
    DECL_A DECL_B
    CALL2U
    #define MQ4(i) { \
      s.x += (float)(i)*(a##i.x*a##i.x + a##i.y*a##i.y + b##i.x*b##i.x + b##i.y*b##i.y); \
      s.y += (float)(i)*(a##i.z*a##i.z + a##i.w*a##i.w + b##i.z*b##i.z + b##i.w*b##i.w); }
    MQ4(1) MQ4(2) MQ4(3) MQ4(4) MQ4(5) MQ4(6) MQ4(7) MQ4(8) MQ4(9)
    #undef MQ4
  }
  return s;
}

// Beamsplitter: photon-number-conserving anti-diagonal blocks.
__device__ __forceinline__ void applyBS4(v4f* S, const cxf* __restrict__ BSp, int m1, int m2, int tid){
  int ra=-1, rb=-1;
  for (int q=0;q<4;q++) if (q!=m1 && q!=m2){ if (ra<0) ra=q; else rb=q; }
  const int sa0 = WS(ra), sb0 = WS(rb);
  const bool sw = (sa0==101 && sb0==10);
  const int sa = sw ? sb0 : sa0, sb = sw ? sa0 : sb0;
  const int s1 = WS(m1), s2 = WS(m2);
  const int ds = s1 - s2;
  #pragma unroll 1
  for (int w0=0; w0<2048; w0+=NTB){
    int it = w0 + tid;
    if (it < 1900){
      int bn = it/100, rest = it-100*bn;
      int ilo = bn<10?0:bn-9, ihi = bn<10?bn:9, sz = ihi-ilo+1;
      int ca = rest/10, cb = rest-10*ca;
      int base = ca*sa + cb*sb;
      const cxf* __restrict__ Bt = BSp + bn*100;   // transposed, zero-padded
      DECL_A
      int radr = base + ilo*s1 + (bn-ilo)*s2;
      int kk = 0;
      #pragma unroll 1
      for (int c=0;c<sz;c++){
        v4f rk = S[radr];
        const v4f* Bp = (const v4f*)(Bt + kk);     // 80B row, 16B aligned
        v4f q0=Bp[0],q1=Bp[1],q2=Bp[2],q3=Bp[3],q4=Bp[4];
        v4f vv=rk, vs=SHUF4(rk);
        CROW_A
        radr += ds; kk += 10;
      }
      int wadr = base + ilo*s1 + (bn-ilo)*s2;
      { if (0 < sz){ S[wadr]=a0; wadr+=ds; } if (1 < sz){ S[wadr]=a1; wadr+=ds; }
        if (2 < sz){ S[wadr]=a2; wadr+=ds; } if (3 < sz){ S[wadr]=a3; wadr+=ds; }
        if (4 < sz){ S[wadr]=a4; wadr+=ds; } if (5 < sz){ S[wadr]=a5; wadr+=ds; }
        if (6 < sz){ S[wadr]=a6; wadr+=ds; } if (7 < sz){ S[wadr]=a7; wadr+=ds; }
        if (8 < sz){ S[wadr]=a8; wadr+=ds; } if (9 < sz){ S[wadr]=a9; wadr+=ds; } }
    }
  }
}

__global__ __launch_bounds__(NTB)
__attribute__((amdgpu_waves_per_eu(2)))
void state_kernel(const float* __restrict__ wd, const float* __restrict__ bd,
                  const float* __restrict__ wsf, float* __restrict__ out){
  extern __shared__ __align__(16) char smem[];
  v4f* S    = (v4f*)smem;                  // 10099 v4f (161584 B)
  cxf* uv   = (cxf*)(smem + 161584);       // 2 states * 4*10 encoding vectors
  v2f* red  = (v2f*)(smem + 162224);       // 8 waves

  const float* __restrict__ V   = wsf;            // for V^T gate
  const float* __restrict__ VT  = wsf + 100;      // for V gate
  const float* __restrict__ W   = wsf + 200;
  const cxf*   __restrict__ BSm = (const cxf*)(wsf + 1200);
  const cxf*   __restrict__ UL  = (const cxf*)(wsf + 5000);
  const cxf*   __restrict__ WU  = (const cxf*)(wsf + 9800);
  const cxf*   __restrict__ uw  = (const cxf*)(wsf + U_OFF);

  const int tid = threadIdx.x, wv = tid>>6, lane = tid&63;
  const int b = blockIdx.x;                // batch items 2b, 2b+1

  if (tid < 80) uv[tid] = uw[b*80 + tid];
  __syncthreads();

  // Init: both product states, interleaved {re0,im0,re1,im1}.
  for (int e=tid; e<10000; e+=NTB){
    int c0=e/1000, r_=e-1000*c0, c1=r_/100, r2_=r_-100*c1, c2=r2_/10, c3=r2_-10*c2;
    cxf A0 = uv[c0],    B0 = uv[10+c1], C0 = uv[20+c2], D0 = uv[30+c3];
    cxf A1 = uv[40+c0], B1 = uv[50+c1], C1 = uv[60+c2], D1 = uv[70+c3];
    float pr = A0.x*B0.x - A0.y*B0.y, pi = A0.x*B0.y + A0.y*B0.x;
    float qr = pr*C0.x - pi*C0.y,  qi = pr*C0.y + pi*C0.x;
    float e0r = qr*D0.x - qi*D0.y, e0i = qr*D0.y + qi*D0.x;
    pr = A1.x*B1.x - A1.y*B1.y; pi = A1.x*B1.y + A1.y*B1.x;
    qr = pr*C1.x - pi*C1.y;  qi = pr*C1.y + pi*C1.x;
    float e1r = qr*D1.x - qi*D1.y, e1i = qr*D1.y + qi*D1.x;
    S[c0*1010 + c1*101 + c2*10 + c3] = (v4f){e0r, e0i, e1r, e1i};
  }
  __syncthreads();

  // ---------------- Layer 0 ----------------
  applyW4(S, W, 0, 1, tid); __syncthreads();
  applyW4(S, W, 0, 2, tid); __syncthreads();
  applyW4(S, W, 0, 3, tid); __syncthreads();
  apply1_r4(S, VT, 0, tid); __syncthreads();      // V0
  apply1_r4(S, V, 1, tid);  __syncthreads();      // V1^T
  applyW4(S, W, 1, 2, tid); __syncthreads();
  applyW4(S, W, 1, 3, tid); __syncthreads();
  apply1_r4(S, VT, 1, tid); __syncthreads();      // V1
  apply1_r4(S, V, 2, tid);  __syncthreads();      // V2^T
  applyW4(S, W, 2, 3, tid); __syncthreads();
  apply1_r4(S, VT, 2, tid); __syncthreads();      // V2
  applyBS4(S, BSm, 0, 1, tid); __syncthreads();
  applyBS4(S, BSm, 1, 2, tid); __syncthreads();
  applyBS4(S, BSm, 2, 3, tid); __syncthreads();
  applyBS4(S, BSm, 3, 0, tid); __syncthreads();
  apply1_c4(S, UL, 0, tid); __syncthreads();      // UL0_L0 (carries L1's V0^T)

  // ---------------- Layer 1 ----------------
  applyWU4(S, WU,        1, tid); __syncthreads();
  applyWU4(S, WU + 1000, 2, tid); __syncthreads();
  applyWU4(S, WU + 2000, 3, tid); __syncthreads();
  apply1_r4(S, VT, 0, tid); __syncthreads();      // V0
  apply1_r4(S, V, 1, tid);  __syncthreads();      // V1^T
  applyW4(S, W, 1, 2, tid); __syncthreads();
  applyW4(S, W, 1, 3, tid); __syncthreads();
  apply1_r4(S, VT, 1, tid); __syncthreads();      // V1
  apply1_r4(S, V, 2, tid);  __syncthreads();      // V2^T
  applyW4(S, W, 2, 3, tid); __syncthreads();
  apply1_r4(S, VT, 2, tid); __syncthreads();      // V2
  applyBS4(S, BSm, 0, 1, tid); __syncthreads();
  applyBS4(S, BSm, 1, 2, tid); __syncthreads();
  applyBS4(S, BSm, 2, 3, tid); __syncthreads();
  applyBS4(S, BSm, 3, 0, tid); __syncthreads();

  // Fused measurement: UL[L1,m] applied read-only; UL[L1,3] dropped.
  float w0 = wd[0], w1 = wd[1], w2 = wd[2];
  v2f m0 = measure14(S, UL + 400, 0, tid);
  v2f m1 = measure14(S, UL + 500, 1, tid);
  v2f m2 = measure14(S, UL + 600, 2, tid);
  v2f acc;
  acc.x = w0*m0.x + w1*m1.x + w2*m2.x;
  acc.y = w0*m0.y + w1*m1.y + w2*m2.y;

  for (int off=32; off; off>>=1){
    acc.x += __shfl_down(acc.x, off, 64);
    acc.y += __shfl_down(acc.y, off, 64);
  }
  if (lane == 0) red[wv] = acc;
  __syncthreads();
  if (tid == 0){
    float sx = 0.f, sy = 0.f;
    for (int i=0;i<8;i++){ sx += red[i].x; sy += red[i].y; }
    out[2*b+0] = sx + bd[0];
    out[2*b+1] = sy + bd[0];
  }
}

} // anonymous namespace

extern "C" void kernel_launch(void* const* d_in, const int* in_sizes, int n_in,
                              void* d_out, int out_size, void* d_ws, size_t ws_size,
                              hipStream_t stream){
  const float* jets   = (const float*)d_in[0];
  const float* sscale = (const float*)d_in[1];
  const float* dmag   = (const float*)d_in[2];
  const float* dphase = (const float*)d_in[3];
  const float* smag   = (const float*)d_in[4];
  const float* sphase = (const float*)d_in[5];
  const float* wd     = (const float*)d_in[6];
  const float* bd     = (const float*)d_in[7];
  float* out = (float*)d_out;
  float* wsf = (float*)d_ws;
  int B = in_sizes[0] / 12;

  (void)hipFuncSetAttribute(reinterpret_cast<const void*>(&state_kernel),
                            hipFuncAttributeMaxDynamicSharedMemorySize, SMEM_STATE);

  gates_kernel<<<12, 256, 0, stream>>>(dmag, dphase, smag, sphase, wsf);
  fuse_kernel<<<1, 512, 0, stream>>>(wsf);
  enc_kernel<<<B*4, 128, 0, stream>>>(jets, sscale, wsf);
  state_kernel<<<B/2, NTB, SMEM_STATE, stream>>>(wd, bd, wsf, out);
}

// Round 8
// 860.812 us; speedup vs baseline: 1.0809x; 1.0809x over previous
//
#include <hip/hip_runtime.h>
#include <math.h>

// CV-photonic circuit: WIRES=4, LAYERS=2, CUTOFF=10, BATCH=2048.
// R21 = R18 exact revert (best measured: 681us state / 857 total:
//  1024 thr, 2 batch-states/thread v4f LDS, padded strides, hoisted
//  ds_read_b128, dwordx4 matrix loads, elementwise_fma) + R20's
//  bank-conflict digit swaps ONLY (the one counter-positive piece of R20:
//  conflicts 2.85e7 -> 2.34e7): in W(0,3)/WU(3)/BS(3,0) swap (qa,qb) so
//  the 101-stride axis is lane-fastest (101 mod 8 = 5, odd -> full octet
//  coverage for b128). Geometry lessons: 2 blocks/CU (R17), 8 waves
//  (R20), pk-asm (R15/R19), generic loop (R16) all regressed — the
//  16-wave 1-block convoy with 2-state amortization is the optimum.

namespace {

constexpr int NTB = 1024;                 // threads per state block (16 waves)
constexpr int SMEM_STATE = 162352;        // 161584 state + 640 uv + 128 red
constexpr double THETA = 0.7853981633974483096; // pi/4

struct cxf { float x, y; };
typedef float v2f __attribute__((ext_vector_type(2)));
typedef float v4f __attribute__((ext_vector_type(4)));

// ws float layout:
// [0,100)       V    (V[k*10+m]; used directly for the V^T gate)
// [100,200)     VT   (VT[k*10+i] = V[i][k]; used for the V gate)
// [200,1200)    Wt   (10 real 10x10, transposed: Wt[n*100+k*10+i]=W_n[i][k])
// [1200,5000)   BSt  cxf[19*100] zero-padded, transposed
// [5000,6600)   ULt  cxf[8*100]: f=0 (L0 UL0, VT-folded), f=4,5,6 (measure)
// [6600,9800)   stage cxf[16*100] raw S_lay (0..7) / D_lay (8..15)
// [9800,15800)  WUt  cxf[30*100]: WU_{b}[n] transposed, id=(b-1)*10+n
// [15872,...)   u    cxf[B*4*10] encoded per-(b,w) vectors
constexpr int U_OFF = 15872;

__device__ __forceinline__ cxf gen_squeeze_f(int i, int j, float zr, float zi){
  if (j == i+2){ float g = 0.5f*sqrtf((float)((i+1)*(i+2))); return {zr*g, -zi*g}; }
  if (i == j+2){ float g = 0.5f*sqrtf((float)((j+1)*(j+2))); return {-zr*g, -zi*g}; }
  return {0.f, 0.f};
}
__device__ __forceinline__ cxf gen_disp_f(int i, int j, float ar, float ai){
  if (i == j+1){ float g = sqrtf((float)i); return {ar*g, ai*g}; }
  if (j == i+1){ float g = sqrtf((float)j); return {-ar*g, ai*g}; }
  return {0.f, 0.f};
}

// Wave-cooperative fixed-schedule fp32 expm: result = exp(M), n x n (n<=10).
__device__ void expm_f32(bool act, int n, cxf* M, cxf* P, cxf* T, cxf* R, int lane){
  const int n2 = n*n;
  if (act){
    for (int e=lane; e<n2; e+=64){ M[e].x *= 0x1p-10f; M[e].y *= 0x1p-10f; }
    for (int e=lane; e<n2; e+=64){
      P[e] = M[e];
      cxf r = M[e];
      if (e % (n+1) == 0) r.x += 1.f;
      R[e] = r;
    }
  }
  __syncthreads();
  for (int t=2; t<=12; ++t){
    if (act){
      float inv = 1.f/(float)t;
      for (int e=lane; e<n2; e+=64){
        int i = e/n, j = e - i*n;
        float ax=0.f, ay=0.f;
        for (int k=0;k<n;k++){
          cxf p = P[i*n+k], m = M[k*n+j];
          ax += p.x*m.x - p.y*m.y;
          ay += p.x*m.y + p.y*m.x;
        }
        T[e] = {ax*inv, ay*inv};
      }
    }
    __syncthreads();
    { cxf* tmp = P; P = T; T = tmp; }
    if (act){ for (int e=lane; e<n2; e+=64){ R[e].x += P[e].x; R[e].y += P[e].y; } }
    __syncthreads();
  }
  for (int s=0; s<10; ++s){
    if (act){
      for (int e=lane; e<n2; e+=64){
        int i = e/n, j = e - i*n;
        float ax=0.f, ay=0.f;
        for (int k=0;k<n;k++){
          cxf p = R[i*n+k], q = R[k*n+j];
          ax += p.x*q.x - p.y*q.y;
          ay += p.x*q.y + p.y*q.x;
        }
        T[e] = {ax, ay};
      }
    }
    __syncthreads();
    { cxf* tmp = R; R = T; T = tmp; }
    __syncthreads();
  }
}

// ------------- Kernel A: 45 expm tasks fully parallel over 12 blocks -------
__global__ __launch_bounds__(256)
void gates_kernel(const float* __restrict__ dmag, const float* __restrict__ dphase,
                  const float* __restrict__ smag, const float* __restrict__ sphase,
                  float* __restrict__ wsf){
  __shared__ double lam[10];
  __shared__ float scr[4][4][200];      // [wave][buf] cxf[100]
  const int tid = threadIdx.x;
  const int wv = tid >> 6, lane = tid & 63, g = blockIdx.x;
  float* ws_V  = wsf;
  float* ws_VT = wsf + 100;
  float* ws_W  = wsf + 200;
  cxf* ws_BS   = (cxf*)(wsf + 1200);
  cxf* ws_stage= (cxf*)(wsf + 6600);

  if (tid < 10){
    double lo = -6.0, hi = 6.0;
    for (int it=0; it<80; ++it){
      double mid = 0.5*(lo+hi);
      int cnt = 0; double q = 1.0;
      for (int i=0;i<10;i++){
        q = -mid - (i ? (double)i/q : 0.0);
        if (fabs(q) < 1e-300) q = -1e-300;
        if (q < 0.0) cnt++;
      }
      if (cnt > tid) hi = mid; else lo = mid;
    }
    double x = 0.5*(lo+hi);
    double p[10];
    p[0] = 1.0; p[1] = x;
    for (int k=1;k<9;k++) p[k+1] = (x*p[k] - sqrt((double)k)*p[k-1]) * (1.0/sqrt((double)(k+1)));
    double nn=0.0; for (int k=0;k<10;k++) nn += p[k]*p[k];
    double inv = 1.0/sqrt(nn);
    lam[tid] = x;
    if (g == 0){
      for (int k=0;k<10;k++){
        float v = (float)(p[k]*inv);
        ws_V[k*10+tid]  = v;
        ws_VT[tid*10+k] = v;
      }
    }
  }
  __syncthreads();

  int t = g*4 + wv;
  bool act = (t < 45);
  int n = 10, bn = 0, ilo = 0;
  if (act && t >= 10 && t < 29){
    bn = t - 10; ilo = bn < 10 ? 0 : bn - 9;
    int ihi = bn < 10 ? bn : 9;
    n = ihi - ilo + 1;
  }
  cxf* M = (cxf*)scr[wv][0];
  cxf* P = (cxf*)scr[wv][1];
  cxf* T = (cxf*)scr[wv][2];
  cxf* R = (cxf*)scr[wv][3];
  if (act){
    if (t < 10){
      float l = (float)lam[t];   // Q = -0.5*(a - ad)
      for (int e=lane; e<100; e+=64){
        int i=e/10, j=e-10*i;
        float v = 0.f;
        if (j == i+1) v = -0.5f*l*sqrtf((float)(i+1));
        else if (i == j+1) v = 0.5f*l*sqrtf((float)i);
        M[e] = {v, 0.f};
      }
    } else if (t < 29){
      for (int e=lane; e<n*n; e+=64){
        int rr=e/n, c=e-n*rr;
        float v = 0.f;
        if (c == rr+1) v = (float)THETA*sqrtf((float)((ilo+rr+1)*(bn-ilo-rr)));
        else if (rr == c+1) v = (float)THETA*sqrtf((float)((ilo+c+1)*(bn-ilo-c)));
        M[e] = {0.f, v};
      }
    } else {
      int idx = t-29, kind = idx>>3, L=(idx>>2)&1, w=idx&3;
      float r_ = kind ? dmag[L*4+w]   : smag[L*4+w];
      float ph = kind ? dphase[L*4+w] : sphase[L*4+w];
      float zr = r_*cosf(ph), zi = r_*sinf(ph);
      for (int e=lane; e<100; e+=64){
        int i=e/10, j=e-10*i;
        M[e] = kind ? gen_disp_f(i,j,zr,zi) : gen_squeeze_f(i,j,zr,zi);
      }
    }
  }
  __syncthreads();
  expm_f32(act, n, M, P, T, R, lane);
  if (act){
    if (t < 10){
      for (int e=lane;e<100;e+=64){
        int i=e/10, j=e-10*i;
        ws_W[t*100 + j*10 + i] = R[e].x;   // transposed, real
      }
    } else if (t < 29){
      for (int e=lane;e<100;e+=64){
        int rr=e/10, c=e-10*rr;
        cxf o; o.x=0.f; o.y=0.f;
        if (rr < n && c < n) o = R[rr*n+c];
        ws_BS[bn*100 + c*10 + rr] = o;     // zero-padded + transposed
      }
    } else {
      int idx = t-29;
      for (int e=lane;e<100;e+=64) ws_stage[idx*100 + e] = R[e];
    }
  }
}

// ---- Kernel A2: UL products, VT fold, and WU_b[n] = W_n * UL_b fusion -----
__global__ __launch_bounds__(512)
void fuse_kernel(float* __restrict__ wsf){
  __shared__ cxf ulraw[8][100];          // raw UL[f] = D*S, [i*10+j]
  const int tid = threadIdx.x, wv = tid>>6, lane = tid&63;
  const cxf* stage = (const cxf*)(wsf + 6600);
  cxf* ws_UL = (cxf*)(wsf + 5000);
  cxf* ws_WU = (cxf*)(wsf + 9800);
  const float* V  = wsf;
  const float* Wt = wsf + 200;
  const cxf* Sm = stage + wv*100;
  const cxf* Dm = stage + (8+wv)*100;
  for (int e=lane; e<100; e+=64){
    int i=e/10, j=e-10*i;
    float ax=0.f, ay=0.f;
    for (int k=0;k<10;k++){
      cxf d=Dm[i*10+k], s=Sm[k*10+j];
      ax += d.x*s.x - d.y*s.y;
      ay += d.x*s.y + d.y*s.x;
    }
    ulraw[wv][e] = {ax, ay};
  }
  __syncthreads();
  // f=0 only: UL0 <- V^T * UL0 (carries L1's V0^T). Two elems per lane.
  cxf t0={0.f,0.f}, t1={0.f,0.f};
  if (wv == 0){
    {
      int e=lane, i=e/10, j=e-10*i;
      float ox=0.f, oy=0.f;
      for (int k=0;k<10;k++){ float v=V[k*10+i]; ox+=v*ulraw[0][k*10+j].x; oy+=v*ulraw[0][k*10+j].y; }
      t0 = {ox, oy};
    }
    if (lane+64 < 100){
      int e=lane+64, i=e/10, j=e-10*i;
      float ox=0.f, oy=0.f;
      for (int k=0;k<10;k++){ float v=V[k*10+i]; ox+=v*ulraw[0][k*10+j].x; oy+=v*ulraw[0][k*10+j].y; }
      t1 = {ox, oy};
    }
  }
  __syncthreads();
  if (wv == 0){
    ulraw[0][lane] = t0;
    if (lane+64 < 100) ulraw[0][lane+64] = t1;
  }
  __syncthreads();
  // Export ULt (transposed) for f in {0,4,5,6}
  for (int e=tid; e<400; e+=512){
    int fi = e/100, r = e-100*fi;
    int f = (fi==0) ? 0 : (3+fi);        // 0,4,5,6
    int i=r/10, j=r-10*i;
    ws_UL[f*100 + j*10 + i] = ulraw[f][i*10+j];
  }
  // Phase 2: WU_b[n] = W_n * ulraw[b], id=(b-1)*10+n, 30 tasks over 8 waves.
  for (int round=0; round<4; ++round){
    int id = round*8 + wv;
    if (id < 30){
      int b = 1 + id/10, n = id - (id/10)*10;
      const cxf* Ub = ulraw[b];
      for (int e=lane; e<100; e+=64){
        int i=e/10, j=e-10*i;
        float ax=0.f, ay=0.f;
        for (int k=0;k<10;k++){
          float w = Wt[n*100 + k*10 + i];   // W_n[i][k]
          ax += w*Ub[k*10+j].x;
          ay += w*Ub[k*10+j].y;
        }
        cxf o; o.x=ax; o.y=ay;
        ws_WU[id*100 + j*10 + i] = o;       // transposed
      }
    }
  }
}

// ------------- Kernel B: per-(b,w) encoding vector u = D*(S*e0), fp32 ------
__global__ __launch_bounds__(128)
void enc_kernel(const float* __restrict__ jets, const float* __restrict__ sscale,
                float* __restrict__ wsf){
  __shared__ float scr[2][4][200];
  __shared__ cxf col[10];
  __shared__ cxf uacc[10];
  const int tid = threadIdx.x, wv = tid>>6, lane = tid&63;
  const int blk = blockIdx.x, b = blk>>2, w = blk&3;

  float eta = jets[b*12 + w*3 + 0];
  float jph = jets[b*12 + w*3 + 1];
  float pt  = jets[b*12 + w*3 + 2];

  cxf* M = (cxf*)scr[wv][0];
  cxf* P = (cxf*)scr[wv][1];
  cxf* T = (cxf*)scr[wv][2];
  cxf* R = (cxf*)scr[wv][3];
  {
    float zr, zi;
    if (wv == 0){ float phs = pt*jph*0.5f; zr = eta*cosf(phs); zi = eta*sinf(phs); }
    else {
      double sc = 10.0/(1.0 + exp(-(double)sscale[0])) + 0.01;
      float mag = (float)sc*pt; zr = mag*cosf(eta); zi = mag*sinf(eta);
    }
    for (int e=lane; e<100; e+=64){
      int i=e/10, j=e-10*i;
      M[e] = wv ? gen_disp_f(i,j,zr,zi) : gen_squeeze_f(i,j,zr,zi);
    }
  }
  __syncthreads();
  expm_f32(true, 10, M, P, T, R, lane);
  cxf* Rs = (cxf*)scr[0][3];
  cxf* Rd = (cxf*)scr[1][3];
  if (tid < 10) col[tid] = Rs[tid*10];           // squeeze column 0
  __syncthreads();
  if (tid < 10){
    float ax=0.f, ay=0.f;
    for (int k=0;k<10;k++){
      cxf d = Rd[tid*10+k], c = col[k];
      ax += d.x*c.x - d.y*c.y;
      ay += d.x*c.y + d.y*c.x;
    }
    uacc[tid] = {ax, ay};
  }
  __syncthreads();
  if (tid < 10){
    float rx, ry;
    if (w == 0){
      rx = 0.f; ry = 0.f;
      for (int k=0;k<10;k++){
        float v = wsf[k*10 + tid];               // (V^T)[tid][k]
        rx += v*uacc[k].x;
        ry += v*uacc[k].y;
      }
    } else { rx = uacc[tid].x; ry = uacc[tid].y; }
    float* u_out = wsf + U_OFF + (b*40 + w*10 + tid)*2;
    u_out[0] = rx;
    u_out[1] = ry;
  }
}

// ---------------- Kernel C: the circuit, 2 states/block, v4f LDS -----------
// Padded digit strides: element (c0,c1,c2,c3) -> c0*1010 + c1*101 + c2*10 + c3.
// idx%8 = (2c0+5c1+2c2+c3)%8 spreads 16B slots across the 128B LDS row.
__device__ __forceinline__ constexpr int WS(int w){
  return w==0 ? 1010 : (w==1 ? 101 : (w==2 ? 10 : 1));
}

#define DECL_ACC4 \
  v4f a0={0.f,0.f,0.f,0.f}, a1=a0, a2=a0, a3=a0, a4=a0, \
      a5=a0, a6=a0, a7=a0, a8=a0, a9=a0;

// hoisted state reads: all 10 ds_read_b128 issued before any math
#define LDS_RD10 \
  v4f r0=S[base], r1=S[base+sm], r2=S[base+2*sm], r3=S[base+3*sm], r4=S[base+4*sm], \
      r5=S[base+5*sm], r6=S[base+6*sm], r7=S[base+7*sm], r8=S[base+8*sm], r9=S[base+9*sm];

// complex element fma on both interleaved states
#define CE(i,ur,ui) \
  a##i = __builtin_elementwise_fma((v4f){(ur),(ur),(ur),(ur)}, vv, a##i); \
  a##i = __builtin_elementwise_fma((v4f){-(ui),(ui),-(ui),(ui)}, vs, a##i);
#define RE(i,u) a##i = __builtin_elementwise_fma((v4f){(u),(u),(u),(u)}, vv, a##i);

// one complex k-step: matrix row krow loaded as 5 dwordx4 (10 cxf)
#define CSTEP(rk,krow) { \
  const v4f* Up = (const v4f*)(U + (krow)*10); \
  v4f q0=Up[0],q1=Up[1],q2=Up[2],q3=Up[3],q4=Up[4]; \
  v4f vv=rk, vs=__builtin_shufflevector(rk,rk,1,0,3,2); \
  CE(0,q0.x,q0.y) CE(1,q0.z,q0.w) CE(2,q1.x,q1.y) CE(3,q1.z,q1.w) \
  CE(4,q2.x,q2.y) CE(5,q2.z,q2.w) CE(6,q3.x,q3.y) CE(7,q3.z,q3.w) \
  CE(8,q4.x,q4.y) CE(9,q4.z,q4.w) }
#define CSTEP_ALL CSTEP(r0,0) CSTEP(r1,1) CSTEP(r2,2) CSTEP(r3,3) CSTEP(r4,4) \
  CSTEP(r5,5) CSTEP(r6,6) CSTEP(r7,7) CSTEP(r8,8) CSTEP(r9,9)

// two real k-steps: rows krow,krow+1 (20 floats) loaded as 5 dwordx4
#define RSTEP2(ra_,rb_,krow) { \
  const v4f* Mp = (const v4f*)(Mt + (krow)*10); \
  v4f q0=Mp[0],q1=Mp[1],q2=Mp[2],q3=Mp[3],q4=Mp[4]; \
  { v4f vv=ra_; RE(0,q0.x) RE(1,q0.y) RE(2,q0.z) RE(3,q0.w) RE(4,q1.x) \
                RE(5,q1.y) RE(6,q1.z) RE(7,q1.w) RE(8,q2.x) RE(9,q2.y) } \
  { v4f vv=rb_; RE(0,q2.z) RE(1,q2.w) RE(2,q3.x) RE(3,q3.y) RE(4,q3.z) \
                RE(5,q3.w) RE(6,q4.x) RE(7,q4.y) RE(8,q4.z) RE(9,q4.w) } }
#define RSTEP_ALL RSTEP2(r0,r1,0) RSTEP2(r2,r3,2) RSTEP2(r4,r5,4) \
  RSTEP2(r6,r7,6) RSTEP2(r8,r9,8)

#define PST4(i) { S[base + (i)*sm] = a##i; }
#define PALL4 PST4(0) PST4(1) PST4(2) PST4(3) PST4(4) PST4(5) PST4(6) PST4(7) PST4(8) PST4(9)
#define BSTQ(r) if ((r) < sz){ S[wadr] = a##r; wadr += ds; }
#define BSTQ_ALL BSTQ(0) BSTQ(1) BSTQ(2) BSTQ(3) BSTQ(4) BSTQ(5) BSTQ(6) BSTQ(7) BSTQ(8) BSTQ(9)

// Uniform/conditional complex gate (UL0): U points at this thread's matrix.
__device__ __forceinline__ void apply1_c4(v4f* S, const cxf* __restrict__ U, int m, int tid){
  const int sm = WS(m);
  const int x0 = (m==0)?1:0, x1=(m<=1)?2:1, x2=(m<=2)?3:2;
  const int s0 = WS(x0), s1 = WS(x1), s2 = WS(x2);
  if (tid < 1000){
    int c0=tid/100, rem=tid-100*c0, c1=rem/10, c2=rem-10*c1;
    int base = c0*s0 + c1*s1 + c2*s2;
    LDS_RD10
    DECL_ACC4
    CSTEP_ALL
    PALL4
  }
}

// Uniform real gate (V / V^T).
__device__ __forceinline__ void apply1_r4(v4f* S, const float* __restrict__ Mt, int m, int tid){
  const int sm = WS(m);
  const int x0 = (m==0)?1:0, x1=(m<=1)?2:1, x2=(m<=2)?3:2;
  const int s0 = WS(x0), s1 = WS(x1), s2 = WS(x2);
  if (tid < 1000){
    int c0=tid/100, rem=tid-100*c0, c1=rem/10, c2=rem-10*c1;
    int base = c0*s0 + c1*s1 + c2*s2;
    LDS_RD10
    DECL_ACC4
    RSTEP_ALL
    PALL4
  }
}

// Real conditional gate W(m1,m2): matrix W_n selected by c_{m1}.
// (qa,qb) swapped when it makes the 101-stride axis lane-fastest (conflict fix).
__device__ __forceinline__ void applyW4(v4f* S, const float* __restrict__ Wall, int m1, int m2, int tid){
  const int sm  = WS(m2);
  const int sm1 = WS(m1);
  int ra=-1, rb=-1;
  for (int q=0;q<4;q++) if (q!=m1 && q!=m2){ if (ra<0) ra=q; else rb=q; }
  const int sa0 = WS(ra), sb0 = WS(rb);
  const bool sw = (sa0==101 && sb0==10);
  const int sa = sw ? sb0 : sa0, sb = sw ? sa0 : sb0;
  if (tid < 1000){
    int n = tid/100, rem = tid-100*n, qa = rem/10, qb = rem-10*qa;
    int base = n*sm1 + qa*sa + qb*sb;
    const float* __restrict__ Mt = Wall + n*100;   // transposed W_n
    LDS_RD10
    DECL_ACC4
    RSTEP_ALL
    PALL4
  }
}

// Complex conditional gate on m2 selected by c0: WU_b[n] = W_n*UL_b.
__device__ __forceinline__ void applyWU4(v4f* S, const cxf* __restrict__ WUall, int m2, int tid){
  const int sm = WS(m2);
  const int ra = (m2==1)?2:1;
  const int rb = (m2==3)?2:3;
  const int sa0 = WS(ra), sb0 = WS(rb);
  const bool sw = (sa0==101 && sb0==10);
  const int sa = sw ? sb0 : sa0, sb = sw ? sa0 : sb0;
  if (tid < 1000){
    int n = tid/100, rem = tid-100*n, qa = rem/10, qb = rem-10*qa;
    int base = n*WS(0) + qa*sa + qb*sb;
    const cxf* __restrict__ U = WUall + n*100;     // transposed complex
    LDS_RD10
    DECL_ACC4
    CSTEP_ALL
    PALL4
  }
}

// Read-only measure: per-state sum_i i*|(U v)_i|^2 over this thread's fiber.
__device__ __forceinline__ v2f measure14(const v4f* S, const cxf* __restrict__ U, int m, int tid){
  const int sm = WS(m);
  const int x0 = (m==0)?1:0, x1=(m<=1)?2:1, x2=3;
  const int s0 = WS(x0), s1 = WS(x1), s2 = WS(x2);
  v2f s = {0.f, 0.f};
  if (tid < 1000){
    int c0=tid/100, rem=tid-100*c0, c1=rem/10, c2=rem-10*c1;
    int base = c0*s0 + c1*s1 + c2*s2;
    LDS_RD10
    DECL_ACC4
    CSTEP_ALL
    #define MQ4(i) { s.x += (float)(i)*(a##i.x*a##i.x + a##i.y*a##i.y); \
                     s.y += (float)(i)*(a##i.z*a##i.z + a##i.w*a##i.w); }
    MQ4(1) MQ4(2) MQ4(3) MQ4(4) MQ4(5) MQ4(6) MQ4(7) MQ4(8) MQ4(9)
    #undef MQ4
  }
  return s;
}

// Beamsplitter: photon-number-conserving anti-diagonal blocks.
__device__ __forceinline__ void applyBS4(v4f* S, const cxf* __restrict__ BSp, int m1, int m2, int tid){
  int ra=-1, rb=-1;
  for (int q=0;q<4;q++) if (q!=m1 && q!=m2){ if (ra<0) ra=q; else rb=q; }
  const int sa0 = WS(ra), sb0 = WS(rb);
  const bool sw = (sa0==101 && sb0==10);
  const int sa = sw ? sb0 : sa0, sb = sw ? sa0 : sb0;
  const int s1 = WS(m1), s2 = WS(m2);
  const int ds = s1 - s2;
  #pragma unroll 1
  for (int w0=0; w0<2048; w0+=NTB){
    int it = w0 + tid;
    if (it < 1900){
      int bn = it/100, rest = it-100*bn;
      int ilo = bn<10?0:bn-9, ihi = bn<10?bn:9, sz = ihi-ilo+1;
      int ca = rest/10, cb = rest-10*ca;
      int base = ca*sa + cb*sb;
      const cxf* __restrict__ Bt = BSp + bn*100;   // transposed, zero-padded
      DECL_ACC4
      int radr = base + ilo*s1 + (bn-ilo)*s2;
      int kk = 0;
      #pragma unroll 1
      for (int c=0;c<sz;c++){
        v4f vv = S[radr];
        v4f vs = __builtin_shufflevector(vv, vv, 1, 0, 3, 2);
        const v4f* Bp = (const v4f*)(Bt + kk);     // 80B row, 16B aligned
        v4f q0=Bp[0],q1=Bp[1],q2=Bp[2],q3=Bp[3],q4=Bp[4];
        CE(0,q0.x,q0.y) CE(1,q0.z,q0.w) CE(2,q1.x,q1.y) CE(3,q1.z,q1.w)
        CE(4,q2.x,q2.y) CE(5,q2.z,q2.w) CE(6,q3.x,q3.y) CE(7,q3.z,q3.w)
        CE(8,q4.x,q4.y) CE(9,q4.z,q4.w)
        radr += ds; kk += 10;
      }
      int wadr = base + ilo*s1 + (bn-ilo)*s2;
      BSTQ_ALL
    }
  }
}

__global__ __launch_bounds__(NTB)
__attribute__((amdgpu_waves_per_eu(4)))
void state_kernel(const float* __restrict__ wd, const float* __restrict__ bd,
                  const float* __restrict__ wsf, float* __restrict__ out){
  extern __shared__ __align__(16) char smem[];
  v4f* S    = (v4f*)smem;                  // 10099 v4f (161584 B)
  cxf* uv   = (cxf*)(smem + 161584);       // 2 states * 4*10 encoding vectors
  v2f* red  = (v2f*)(smem + 162224);       // 16 waves

  const float* __restrict__ V   = wsf;            // for V^T gate
  const float* __restrict__ VT  = wsf + 100;      // for V gate
  const float* __restrict__ W   = wsf + 200;
  const cxf*   __restrict__ BSm = (const cxf*)(wsf + 1200);
  const cxf*   __restrict__ UL  = (const cxf*)(wsf + 5000);
  const cxf*   __restrict__ WU  = (const cxf*)(wsf + 9800);
  const cxf*   __restrict__ uw  = (const cxf*)(wsf + U_OFF);

  const int tid = threadIdx.x, wv = tid>>6, lane = tid&63;
  const int b = blockIdx.x;                // batch items 2b, 2b+1

  if (tid < 80) uv[tid] = uw[b*80 + tid];
  __syncthreads();

  // Init: both product states, interleaved {re0,im0,re1,im1}.
  for (int e=tid; e<10000; e+=NTB){
    int c0=e/1000, r_=e-1000*c0, c1=r_/100, r2_=r_-100*c1, c2=r2_/10, c3=r2_-10*c2;
    cxf A0 = uv[c0],    B0 = uv[10+c1], C0 = uv[20+c2], D0 = uv[30+c3];
    cxf A1 = uv[40+c0], B1 = uv[50+c1], C1 = uv[60+c2], D1 = uv[70+c3];
    float pr = A0.x*B0.x - A0.y*B0.y, pi = A0.x*B0.y + A0.y*B0.x;
    float qr = pr*C0.x - pi*C0.y,  qi = pr*C0.y + pi*C0.x;
    float e0r = qr*D0.x - qi*D0.y, e0i = qr*D0.y + qi*D0.x;
    pr = A1.x*B1.x - A1.y*B1.y; pi = A1.x*B1.y + A1.y*B1.x;
    qr = pr*C1.x - pi*C1.y;  qi = pr*C1.y + pi*C1.x;
    float e1r = qr*D1.x - qi*D1.y, e1i = qr*D1.y + qi*D1.x;
    S[c0*1010 + c1*101 + c2*10 + c3] = (v4f){e0r, e0i, e1r, e1i};
  }
  __syncthreads();

  // ---------------- Layer 0 ----------------
  applyW4(S, W, 0, 1, tid); __syncthreads();
  applyW4(S, W, 0, 2, tid); __syncthreads();
  applyW4(S, W, 0, 3, tid); __syncthreads();
  apply1_r4(S, VT, 0, tid); __syncthreads();      // V0
  apply1_r4(S, V, 1, tid);  __syncthreads();      // V1^T
  applyW4(S, W, 1, 2, tid); __syncthreads();
  applyW4(S, W, 1, 3, tid); __syncthreads();
  apply1_r4(S, VT, 1, tid); __syncthreads();      // V1
  apply1_r4(S, V, 2, tid);  __syncthreads();      // V2^T
  applyW4(S, W, 2, 3, tid); __syncthreads();
  apply1_r4(S, VT, 2, tid); __syncthreads();      // V2
  applyBS4(S, BSm, 0, 1, tid); __syncthreads();
  applyBS4(S, BSm, 1, 2, tid); __syncthreads();
  applyBS4(S, BSm, 2, 3, tid); __syncthreads();
  applyBS4(S, BSm, 3, 0, tid); __syncthreads();
  apply1_c4(S, UL, 0, tid); __syncthreads();      // UL0_L0 (carries L1's V0^T)

  // ---------------- Layer 1 ----------------
  applyWU4(S, WU,        1, tid); __syncthreads();
  applyWU4(S, WU + 1000, 2, tid); __syncthreads();
  applyWU4(S, WU + 2000, 3, tid); __syncthreads();
  apply1_r4(S, VT, 0, tid); __syncthreads();      // V0
  apply1_r4(S, V, 1, tid);  __syncthreads();      // V1^T
  applyW4(S, W, 1, 2, tid); __syncthreads();
  applyW4(S, W, 1, 3, tid); __syncthreads();
  apply1_r4(S, VT, 1, tid); __syncthreads();      // V1
  apply1_r4(S, V, 2, tid);  __syncthreads();      // V2^T
  applyW4(S, W, 2, 3, tid); __syncthreads();
  apply1_r4(S, VT, 2, tid); __syncthreads();      // V2
  applyBS4(S, BSm, 0, 1, tid); __syncthreads();
  applyBS4(S, BSm, 1, 2, tid); __syncthreads();
  applyBS4(S, BSm, 2, 3, tid); __syncthreads();
  applyBS4(S, BSm, 3, 0, tid); __syncthreads();

  // Fused measurement: UL[L1,m] applied read-only; UL[L1,3] dropped.
  float w0 = wd[0], w1 = wd[1], w2 = wd[2];
  v2f m0 = measure14(S, UL + 400, 0, tid);
  v2f m1 = measure14(S, UL + 500, 1, tid);
  v2f m2 = measure14(S, UL + 600, 2, tid);
  v2f acc;
  acc.x = w0*m0.x + w1*m1.x + w2*m2.x;
  acc.y = w0*m0.y + w1*m1.y + w2*m2.y;

  for (int off=32; off; off>>=1){
    acc.x += __shfl_down(acc.x, off, 64);
    acc.y += __shfl_down(acc.y, off, 64);
  }
  if (lane == 0) red[wv] = acc;
  __syncthreads();
  if (tid == 0){
    float sx = 0.f, sy = 0.f;
    for (int i=0;i<16;i++){ sx += red[i].x; sy += red[i].y; }
    out[2*b+0] = sx + bd[0];
    out[2*b+1] = sy + bd[0];
  }
}

} // anonymous namespace

extern "C" void kernel_launch(void* const* d_in, const int* in_sizes, int n_in,
                              void* d_out, int out_size, void* d_ws, size_t ws_size,
                              hipStream_t stream){
  const float* jets   = (const float*)d_in[0];
  const float* sscale = (const float*)d_in[1];
  const float* dmag   = (const float*)d_in[2];
  const float* dphase = (const float*)d_in[3];
  const float* smag   = (const float*)d_in[4];
  const float* sphase = (const float*)d_in[5];
  const float* wd     = (const float*)d_in[6];
  const float* bd     = (const float*)d_in[7];
  float* out = (float*)d_out;
  float* wsf = (float*)d_ws;
  int B = in_sizes[0] / 12;

  (void)hipFuncSetAttribute(reinterpret_cast<const void*>(&state_kernel),
                            hipFuncAttributeMaxDynamicSharedMemorySize, SMEM_STATE);

  gates_kernel<<<12, 256, 0, stream>>>(dmag, dphase, smag, sphase, wsf);
  fuse_kernel<<<1, 512, 0, stream>>>(wsf);
  enc_kernel<<<B*4, 128, 0, stream>>>(jets, sscale, wsf);
  state_kernel<<<B/2, NTB, SMEM_STATE, stream>>>(wd, bd, wsf, out);
}

// Round 9
// 845.779 us; speedup vs baseline: 1.1001x; 1.0178x over previous
//
#include <hip/hip_runtime.h>
#include <math.h>

// CV-photonic circuit: WIRES=4, LAYERS=2, CUTOFF=10, BATCH=2048.
// R22 = R21 (best: 679us state; 1024 thr, 2 batch-states v4f LDS, padded
//  strides, hoisted ds_read_b128, dwordx4 loads, conflict swaps) +
//  GATE FUSION via commutation: same-wire gate runs register-chain into
//  one pass (1 read + k matvecs + 1 write + 1 barrier). Per layer the 11
//  single-wire passes become 3 mega + 3 V passes:
//   [W(0,1)->V1^T] w1, [W(0,2)->W(1,2)->V2^T] w2, [W(0,3)->W(1,3)->W(2,3)] w3,
//   then V0,V1,V2 (commutation-verified exact reorder). L1 same with WU(b).
//  Pass count 34 -> 24; VALU (pk) count unchanged — R21 analysis: VALU
//  floor = 272K cy of 408K wall (67%), overhead ~4.1K cy/pass x 33.

namespace {

constexpr int NTB = 1024;                 // threads per state block (16 waves)
constexpr int SMEM_STATE = 162352;        // 161584 state + 640 uv + 128 red
constexpr double THETA = 0.7853981633974483096; // pi/4

struct cxf { float x, y; };
typedef float v2f __attribute__((ext_vector_type(2)));
typedef float v4f __attribute__((ext_vector_type(4)));

// ws float layout:
// [0,100)       V    (V[k*10+m]; used directly for the V^T gate)
// [100,200)     VT   (VT[k*10+i] = V[i][k]; used for the V gate)
// [200,1200)    Wt   (10 real 10x10, transposed: Wt[n*100+k*10+i]=W_n[i][k])
// [1200,5000)   BSt  cxf[19*100] zero-padded, transposed
// [5000,6600)   ULt  cxf[8*100]: f=0 (L0 UL0, VT-folded), f=4,5,6 (measure)
// [6600,9800)   stage cxf[16*100] raw S_lay (0..7) / D_lay (8..15)
// [9800,15800)  WUt  cxf[30*100]: WU_{b}[n] transposed, id=(b-1)*10+n
// [15872,...)   u    cxf[B*4*10] encoded per-(b,w) vectors
constexpr int U_OFF = 15872;

__device__ __forceinline__ cxf gen_squeeze_f(int i, int j, float zr, float zi){
  if (j == i+2){ float g = 0.5f*sqrtf((float)((i+1)*(i+2))); return {zr*g, -zi*g}; }
  if (i == j+2){ float g = 0.5f*sqrtf((float)((j+1)*(j+2))); return {-zr*g, -zi*g}; }
  return {0.f, 0.f};
}
__device__ __forceinline__ cxf gen_disp_f(int i, int j, float ar, float ai){
  if (i == j+1){ float g = sqrtf((float)i); return {ar*g, ai*g}; }
  if (j == i+1){ float g = sqrtf((float)j); return {-ar*g, ai*g}; }
  return {0.f, 0.f};
}

// Wave-cooperative fixed-schedule fp32 expm: result = exp(M), n x n (n<=10).
__device__ void expm_f32(bool act, int n, cxf* M, cxf* P, cxf* T, cxf* R, int lane){
  const int n2 = n*n;
  if (act){
    for (int e=lane; e<n2; e+=64){ M[e].x *= 0x1p-10f; M[e].y *= 0x1p-10f; }
    for (int e=lane; e<n2; e+=64){
      P[e] = M[e];
      cxf r = M[e];
      if (e % (n+1) == 0) r.x += 1.f;
      R[e] = r;
    }
  }
  __syncthreads();
  for (int t=2; t<=12; ++t){
    if (act){
      float inv = 1.f/(float)t;
      for (int e=lane; e<n2; e+=64){
        int i = e/n, j = e - i*n;
        float ax=0.f, ay=0.f;
        for (int k=0;k<n;k++){
          cxf p = P[i*n+k], m = M[k*n+j];
          ax += p.x*m.x - p.y*m.y;
          ay += p.x*m.y + p.y*m.x;
        }
        T[e] = {ax*inv, ay*inv};
      }
    }
    __syncthreads();
    { cxf* tmp = P; P = T; T = tmp; }
    if (act){ for (int e=lane; e<n2; e+=64){ R[e].x += P[e].x; R[e].y += P[e].y; } }
    __syncthreads();
  }
  for (int s=0; s<10; ++s){
    if (act){
      for (int e=lane; e<n2; e+=64){
        int i = e/n, j = e - i*n;
        float ax=0.f, ay=0.f;
        for (int k=0;k<n;k++){
          cxf p = R[i*n+k], q = R[k*n+j];
          ax += p.x*q.x - p.y*q.y;
          ay += p.x*q.y + p.y*q.x;
        }
        T[e] = {ax, ay};
      }
    }
    __syncthreads();
    { cxf* tmp = R; R = T; T = tmp; }
    __syncthreads();
  }
}

// ------------- Kernel A: 45 expm tasks fully parallel over 12 blocks -------
__global__ __launch_bounds__(256)
void gates_kernel(const float* __restrict__ dmag, const float* __restrict__ dphase,
                  const float* __restrict__ smag, const float* __restrict__ sphase,
                  float* __restrict__ wsf){
  __shared__ double lam[10];
  __shared__ float scr[4][4][200];      // [wave][buf] cxf[100]
  const int tid = threadIdx.x;
  const int wv = tid >> 6, lane = tid & 63, g = blockIdx.x;
  float* ws_V  = wsf;
  float* ws_VT = wsf + 100;
  float* ws_W  = wsf + 200;
  cxf* ws_BS   = (cxf*)(wsf + 1200);
  cxf* ws_stage= (cxf*)(wsf + 6600);

  if (tid < 10){
    double lo = -6.0, hi = 6.0;
    for (int it=0; it<80; ++it){
      double mid = 0.5*(lo+hi);
      int cnt = 0; double q = 1.0;
      for (int i=0;i<10;i++){
        q = -mid - (i ? (double)i/q : 0.0);
        if (fabs(q) < 1e-300) q = -1e-300;
        if (q < 0.0) cnt++;
      }
      if (cnt > tid) hi = mid; else lo = mid;
    }
    double x = 0.5*(lo+hi);
    double p[10];
    p[0] = 1.0; p[1] = x;
    for (int k=1;k<9;k++) p[k+1] = (x*p[k] - sqrt((double)k)*p[k-1]) * (1.0/sqrt((double)(k+1)));
    double nn=0.0; for (int k=0;k<10;k++) nn += p[k]*p[k];
    double inv = 1.0/sqrt(nn);
    lam[tid] = x;
    if (g == 0){
      for (int k=0;k<10;k++){
        float v = (float)(p[k]*inv);
        ws_V[k*10+tid]  = v;
        ws_VT[tid*10+k] = v;
      }
    }
  }
  __syncthreads();

  int t = g*4 + wv;
  bool act = (t < 45);
  int n = 10, bn = 0, ilo = 0;
  if (act && t >= 10 && t < 29){
    bn = t - 10; ilo = bn < 10 ? 0 : bn - 9;
    int ihi = bn < 10 ? bn : 9;
    n = ihi - ilo + 1;
  }
  cxf* M = (cxf*)scr[wv][0];
  cxf* P = (cxf*)scr[wv][1];
  cxf* T = (cxf*)scr[wv][2];
  cxf* R = (cxf*)scr[wv][3];
  if (act){
    if (t < 10){
      float l = (float)lam[t];   // Q = -0.5*(a - ad)
      for (int e=lane; e<100; e+=64){
        int i=e/10, j=e-10*i;
        float v = 0.f;
        if (j == i+1) v = -0.5f*l*sqrtf((float)(i+1));
        else if (i == j+1) v = 0.5f*l*sqrtf((float)i);
        M[e] = {v, 0.f};
      }
    } else if (t < 29){
      for (int e=lane; e<n*n; e+=64){
        int rr=e/n, c=e-n*rr;
        float v = 0.f;
        if (c == rr+1) v = (float)THETA*sqrtf((float)((ilo+rr+1)*(bn-ilo-rr)));
        else if (rr == c+1) v = (float)THETA*sqrtf((float)((ilo+c+1)*(bn-ilo-c)));
        M[e] = {0.f, v};
      }
    } else {
      int idx = t-29, kind = idx>>3, L=(idx>>2)&1, w=idx&3;
      float r_ = kind ? dmag[L*4+w]   : smag[L*4+w];
      float ph = kind ? dphase[L*4+w] : sphase[L*4+w];
      float zr = r_*cosf(ph), zi = r_*sinf(ph);
      for (int e=lane; e<100; e+=64){
        int i=e/10, j=e-10*i;
        M[e] = kind ? gen_disp_f(i,j,zr,zi) : gen_squeeze_f(i,j,zr,zi);
      }
    }
  }
  __syncthreads();
  expm_f32(act, n, M, P, T, R, lane);
  if (act){
    if (t < 10){
      for (int e=lane;e<100;e+=64){
        int i=e/10, j=e-10*i;
        ws_W[t*100 + j*10 + i] = R[e].x;   // transposed, real
      }
    } else if (t < 29){
      for (int e=lane;e<100;e+=64){
        int rr=e/10, c=e-10*rr;
        cxf o; o.x=0.f; o.y=0.f;
        if (rr < n && c < n) o = R[rr*n+c];
        ws_BS[bn*100 + c*10 + rr] = o;     // zero-padded + transposed
      }
    } else {
      int idx = t-29;
      for (int e=lane;e<100;e+=64) ws_stage[idx*100 + e] = R[e];
    }
  }
}

// ---- Kernel A2: UL products, VT fold, and WU_b[n] = W_n * UL_b fusion -----
__global__ __launch_bounds__(512)
void fuse_kernel(float* __restrict__ wsf){
  __shared__ cxf ulraw[8][100];          // raw UL[f] = D*S, [i*10+j]
  const int tid = threadIdx.x, wv = tid>>6, lane = tid&63;
  const cxf* stage = (const cxf*)(wsf + 6600);
  cxf* ws_UL = (cxf*)(wsf + 5000);
  cxf* ws_WU = (cxf*)(wsf + 9800);
  const float* V  = wsf;
  const float* Wt = wsf + 200;
  const cxf* Sm = stage + wv*100;
  const cxf* Dm = stage + (8+wv)*100;
  for (int e=lane; e<100; e+=64){
    int i=e/10, j=e-10*i;
    float ax=0.f, ay=0.f;
    for (int k=0;k<10;k++){
      cxf d=Dm[i*10+k], s=Sm[k*10+j];
      ax += d.x*s.x - d.y*s.y;
      ay += d.x*s.y + d.y*s.x;
    }
    ulraw[wv][e] = {ax, ay};
  }
  __syncthreads();
  // f=0 only: UL0 <- V^T * UL0 (carries L1's V0^T). Two elems per lane.
  cxf t0={0.f,0.f}, t1={0.f,0.f};
  if (wv == 0){
    {
      int e=lane, i=e/10, j=e-10*i;
      float ox=0.f, oy=0.f;
      for (int k=0;k<10;k++){ float v=V[k*10+i]; ox+=v*ulraw[0][k*10+j].x; oy+=v*ulraw[0][k*10+j].y; }
      t0 = {ox, oy};
    }
    if (lane+64 < 100){
      int e=lane+64, i=e/10, j=e-10*i;
      float ox=0.f, oy=0.f;
      for (int k=0;k<10;k++){ float v=V[k*10+i]; ox+=v*ulraw[0][k*10+j].x; oy+=v*ulraw[0][k*10+j].y; }
      t1 = {ox, oy};
    }
  }
  __syncthreads();
  if (wv == 0){
    ulraw[0][lane] = t0;
    if (lane+64 < 100) ulraw[0][lane+64] = t1;
  }
  __syncthreads();
  // Export ULt (transposed) for f in {0,4,5,6}
  for (int e=tid; e<400; e+=512){
    int fi = e/100, r = e-100*fi;
    int f = (fi==0) ? 0 : (3+fi);        // 0,4,5,6
    int i=r/10, j=r-10*i;
    ws_UL[f*100 + j*10 + i] = ulraw[f][i*10+j];
  }
  // Phase 2: WU_b[n] = W_n * ulraw[b], id=(b-1)*10+n, 30 tasks over 8 waves.
  for (int round=0; round<4; ++round){
    int id = round*8 + wv;
    if (id < 30){
      int b = 1 + id/10, n = id - (id/10)*10;
      const cxf* Ub = ulraw[b];
      for (int e=lane; e<100; e+=64){
        int i=e/10, j=e-10*i;
        float ax=0.f, ay=0.f;
        for (int k=0;k<10;k++){
          float w = Wt[n*100 + k*10 + i];   // W_n[i][k]
          ax += w*Ub[k*10+j].x;
          ay += w*Ub[k*10+j].y;
        }
        cxf o; o.x=ax; o.y=ay;
        ws_WU[id*100 + j*10 + i] = o;       // transposed
      }
    }
  }
}

// ------------- Kernel B: per-(b,w) encoding vector u = D*(S*e0), fp32 ------
__global__ __launch_bounds__(128)
void enc_kernel(const float* __restrict__ jets, const float* __restrict__ sscale,
                float* __restrict__ wsf){
  __shared__ float scr[2][4][200];
  __shared__ cxf col[10];
  __shared__ cxf uacc[10];
  const int tid = threadIdx.x, wv = tid>>6, lane = tid&63;
  const int blk = blockIdx.x, b = blk>>2, w = blk&3;

  float eta = jets[b*12 + w*3 + 0];
  float jph = jets[b*12 + w*3 + 1];
  float pt  = jets[b*12 + w*3 + 2];

  cxf* M = (cxf*)scr[wv][0];
  cxf* P = (cxf*)scr[wv][1];
  cxf* T = (cxf*)scr[wv][2];
  cxf* R = (cxf*)scr[wv][3];
  {
    float zr, zi;
    if (wv == 0){ float phs = pt*jph*0.5f; zr = eta*cosf(phs); zi = eta*sinf(phs); }
    else {
      double sc = 10.0/(1.0 + exp(-(double)sscale[0])) + 0.01;
      float mag = (float)sc*pt; zr = mag*cosf(eta); zi = mag*sinf(eta);
    }
    for (int e=lane; e<100; e+=64){
      int i=e/10, j=e-10*i;
      M[e] = wv ? gen_disp_f(i,j,zr,zi) : gen_squeeze_f(i,j,zr,zi);
    }
  }
  __syncthreads();
  expm_f32(true, 10, M, P, T, R, lane);
  cxf* Rs = (cxf*)scr[0][3];
  cxf* Rd = (cxf*)scr[1][3];
  if (tid < 10) col[tid] = Rs[tid*10];           // squeeze column 0
  __syncthreads();
  if (tid < 10){
    float ax=0.f, ay=0.f;
    for (int k=0;k<10;k++){
      cxf d = Rd[tid*10+k], c = col[k];
      ax += d.x*c.x - d.y*c.y;
      ay += d.x*c.y + d.y*c.x;
    }
    uacc[tid] = {ax, ay};
  }
  __syncthreads();
  if (tid < 10){
    float rx, ry;
    if (w == 0){
      rx = 0.f; ry = 0.f;
      for (int k=0;k<10;k++){
        float v = wsf[k*10 + tid];               // (V^T)[tid][k]
        rx += v*uacc[k].x;
        ry += v*uacc[k].y;
      }
    } else { rx = uacc[tid].x; ry = uacc[tid].y; }
    float* u_out = wsf + U_OFF + (b*40 + w*10 + tid)*2;
    u_out[0] = rx;
    u_out[1] = ry;
  }
}

// ---------------- Kernel C: the circuit, 2 states/block, v4f LDS -----------
// Padded digit strides: element (c0,c1,c2,c3) -> c0*1010 + c1*101 + c2*10 + c3.
__device__ __forceinline__ constexpr int WS(int w){
  return w==0 ? 1010 : (w==1 ? 101 : (w==2 ? 10 : 1));
}

// ---- generic chained-stage building blocks (prefix-named register sets) ----
#define DECLP(P) v4f P##0={0.f,0.f,0.f,0.f}, P##1=P##0, P##2=P##0, P##3=P##0, \
  P##4=P##0, P##5=P##0, P##6=P##0, P##7=P##0, P##8=P##0, P##9=P##0;

#define REX(O,i,u) O##i = __builtin_elementwise_fma((v4f){(u),(u),(u),(u)}, vv, O##i);

#define RPAIRX(O, va, vb, Mp_) { \
  const v4f* Mp = (Mp_); \
  v4f q0=Mp[0],q1=Mp[1],q2=Mp[2],q3=Mp[3],q4=Mp[4]; \
  { v4f vv=va; REX(O,0,q0.x) REX(O,1,q0.y) REX(O,2,q0.z) REX(O,3,q0.w) REX(O,4,q1.x) \
               REX(O,5,q1.y) REX(O,6,q1.z) REX(O,7,q1.w) REX(O,8,q2.x) REX(O,9,q2.y) } \
  { v4f vv=vb; REX(O,0,q2.z) REX(O,1,q2.w) REX(O,2,q3.x) REX(O,3,q3.y) REX(O,4,q3.z) \
               REX(O,5,q3.w) REX(O,6,q4.x) REX(O,7,q4.y) REX(O,8,q4.z) REX(O,9,q4.w) } }

#define RSTAGE(Mt, I, O) \
  RPAIRX(O, I##0, I##1, (const v4f*)((Mt)+0))  \
  RPAIRX(O, I##2, I##3, (const v4f*)((Mt)+20)) \
  RPAIRX(O, I##4, I##5, (const v4f*)((Mt)+40)) \
  RPAIRX(O, I##6, I##7, (const v4f*)((Mt)+60)) \
  RPAIRX(O, I##8, I##9, (const v4f*)((Mt)+80))

#define CEX(O,i,ur,ui) \
  O##i = __builtin_elementwise_fma((v4f){(ur),(ur),(ur),(ur)}, vv, O##i); \
  O##i = __builtin_elementwise_fma((v4f){-(ui),(ui),-(ui),(ui)}, vs, O##i);

#define CROWX(O, vk, Up_) { \
  const v4f* Up = (Up_); \
  v4f q0=Up[0],q1=Up[1],q2=Up[2],q3=Up[3],q4=Up[4]; \
  v4f vv=vk, vs=__builtin_shufflevector(vk,vk,1,0,3,2); \
  CEX(O,0,q0.x,q0.y) CEX(O,1,q0.z,q0.w) CEX(O,2,q1.x,q1.y) CEX(O,3,q1.z,q1.w) \
  CEX(O,4,q2.x,q2.y) CEX(O,5,q2.z,q2.w) CEX(O,6,q3.x,q3.y) CEX(O,7,q3.z,q3.w) \
  CEX(O,8,q4.x,q4.y) CEX(O,9,q4.z,q4.w) }

#define CSTAGE(U, I, O) \
  CROWX(O, I##0, (const v4f*)((U)+0))  CROWX(O, I##1, (const v4f*)((U)+10)) \
  CROWX(O, I##2, (const v4f*)((U)+20)) CROWX(O, I##3, (const v4f*)((U)+30)) \
  CROWX(O, I##4, (const v4f*)((U)+40)) CROWX(O, I##5, (const v4f*)((U)+50)) \
  CROWX(O, I##6, (const v4f*)((U)+60)) CROWX(O, I##7, (const v4f*)((U)+70)) \
  CROWX(O, I##8, (const v4f*)((U)+80)) CROWX(O, I##9, (const v4f*)((U)+90))

#define LDS_RD10 \
  v4f r0=S[base], r1=S[base+sm], r2=S[base+2*sm], r3=S[base+3*sm], r4=S[base+4*sm], \
      r5=S[base+5*sm], r6=S[base+6*sm], r7=S[base+7*sm], r8=S[base+8*sm], r9=S[base+9*sm];

#define PSTORE10(P) { S[base]=P##0; S[base+sm]=P##1; S[base+2*sm]=P##2; S[base+3*sm]=P##3; \
  S[base+4*sm]=P##4; S[base+5*sm]=P##5; S[base+6*sm]=P##6; S[base+7*sm]=P##7; \
  S[base+8*sm]=P##8; S[base+9*sm]=P##9; }

// ---- fused mega-passes -----------------------------------------------------
// w1: [W(0,1) cond c0] -> [V1^T uniform].  fiber (c0,c2,c3), act stride 101.
__device__ __forceinline__ void fuse_w1_r(v4f* S, const float* __restrict__ Wall,
                                          const float* __restrict__ Mu, int tid){
  if (tid < 1000){
    int d0=tid/100, rem=tid-100*d0, d1=rem/10, d2=rem-10*d1;
    const int sm = 101;
    int base = d0*1010 + d1*10 + d2;
    LDS_RD10
    const float* M1 = Wall + d0*100;
    DECLP(a) RSTAGE(M1, r, a)
    DECLP(b) RSTAGE(Mu, a, b)
    PSTORE10(b)
  }
}
// L1 variant: stage1 complex WU(1).
__device__ __forceinline__ void fuse_w1_c(v4f* S, const cxf* __restrict__ WUb,
                                          const float* __restrict__ Mu, int tid){
  if (tid < 1000){
    int d0=tid/100, rem=tid-100*d0, d1=rem/10, d2=rem-10*d1;
    const int sm = 101;
    int base = d0*1010 + d1*10 + d2;
    LDS_RD10
    const cxf* U1 = WUb + d0*100;
    DECLP(a) CSTAGE(U1, r, a)
    DECLP(b) RSTAGE(Mu, a, b)
    PSTORE10(b)
  }
}
// w2: [W(0,2) c0] -> [W(1,2) c1] -> [V2^T].  fiber (c0,c1,c3), act stride 10.
__device__ __forceinline__ void fuse_w2_r(v4f* S, const float* __restrict__ Wall,
                                          const float* __restrict__ Mu, int tid){
  if (tid < 1000){
    int d0=tid/100, rem=tid-100*d0, d1=rem/10, d2=rem-10*d1;
    const int sm = 10;
    int base = d0*1010 + d1*101 + d2;
    LDS_RD10
    const float* M1 = Wall + d0*100;
    const float* M2 = Wall + d1*100;
    DECLP(a) RSTAGE(M1, r, a)
    DECLP(b) RSTAGE(M2, a, b)
    DECLP(c) RSTAGE(Mu, b, c)
    PSTORE10(c)
  }
}
__device__ __forceinline__ void fuse_w2_c(v4f* S, const cxf* __restrict__ WUb,
                                          const float* __restrict__ Wall,
                                          const float* __restrict__ Mu, int tid){
  if (tid < 1000){
    int d0=tid/100, rem=tid-100*d0, d1=rem/10, d2=rem-10*d1;
    const int sm = 10;
    int base = d0*1010 + d1*101 + d2;
    LDS_RD10
    const cxf* U1 = WUb + d0*100;
    const float* M2 = Wall + d1*100;
    DECLP(a) CSTAGE(U1, r, a)
    DECLP(b) RSTAGE(M2, a, b)
    DECLP(c) RSTAGE(Mu, b, c)
    PSTORE10(c)
  }
}
// w3: [W(0,3) c0] -> [W(1,3) c1] -> [W(2,3) c2].  fiber (c0,c1=d2,c2=d1),
// act stride 1; d2 on stride 101 keeps b128 conflict-free (R21 swap).
__device__ __forceinline__ void fuse_w3_r(v4f* S, const float* __restrict__ Wall, int tid){
  if (tid < 1000){
    int d0=tid/100, rem=tid-100*d0, d1=rem/10, d2=rem-10*d1;
    const int sm = 1;
    int base = d0*1010 + d2*101 + d1*10;
    LDS_RD10
    const float* M1 = Wall + d0*100;     // cond c0
    const float* M2 = Wall + d2*100;     // cond c1
    const float* M3 = Wall + d1*100;     // cond c2
    DECLP(a) RSTAGE(M1, r, a)
    DECLP(b) RSTAGE(M2, a, b)
    DECLP(c) RSTAGE(M3, b, c)
    PSTORE10(c)
  }
}
__device__ __forceinline__ void fuse_w3_c(v4f* S, const cxf* __restrict__ WUb,
                                          const float* __restrict__ Wall, int tid){
  if (tid < 1000){
    int d0=tid/100, rem=tid-100*d0, d1=rem/10, d2=rem-10*d1;
    const int sm = 1;
    int base = d0*1010 + d2*101 + d1*10;
    LDS_RD10
    const cxf* U1 = WUb + d0*100;        // cond c0 (complex)
    const float* M2 = Wall + d2*100;     // cond c1
    const float* M3 = Wall + d1*100;     // cond c2
    DECLP(a) CSTAGE(U1, r, a)
    DECLP(b) RSTAGE(M2, a, b)
    DECLP(c) RSTAGE(M3, b, c)
    PSTORE10(c)
  }
}

// ---- uniform single-wire passes -------------------------------------------
__device__ __forceinline__ void apply1_r4(v4f* S, const float* __restrict__ Mt, int m, int tid){
  const int sm = WS(m);
  const int x0 = (m==0)?1:0, x1=(m<=1)?2:1, x2=(m<=2)?3:2;
  const int s0 = WS(x0), s1 = WS(x1), s2 = WS(x2);
  if (tid < 1000){
    int d0=tid/100, rem=tid-100*d0, d1=rem/10, d2=rem-10*d1;
    int base = d0*s0 + d1*s1 + d2*s2;
    LDS_RD10
    DECLP(a) RSTAGE(Mt, r, a)
    PSTORE10(a)
  }
}

__device__ __forceinline__ void apply1_c4(v4f* S, const cxf* __restrict__ U, int m, int tid){
  const int sm = WS(m);
  const int x0 = (m==0)?1:0, x1=(m<=1)?2:1, x2=(m<=2)?3:2;
  const int s0 = WS(x0), s1 = WS(x1), s2 = WS(x2);
  if (tid < 1000){
    int d0=tid/100, rem=tid-100*d0, d1=rem/10, d2=rem-10*d1;
    int base = d0*s0 + d1*s1 + d2*s2;
    LDS_RD10
    DECLP(a) CSTAGE(U, r, a)
    PSTORE10(a)
  }
}

// Read-only measure: per-state sum_i i*|(U v)_i|^2 over this thread's fiber.
__device__ __forceinline__ v2f measure14(const v4f* S, const cxf* __restrict__ U, int m, int tid){
  const int sm = WS(m);
  const int x0 = (m==0)?1:0, x1=(m<=1)?2:1, x2=3;
  const int s0 = WS(x0), s1 = WS(x1), s2 = WS(x2);
  v2f s = {0.f, 0.f};
  if (tid < 1000){
    int d0=tid/100, rem=tid-100*d0, d1=rem/10, d2=rem-10*d1;
    int base = d0*s0 + d1*s1 + d2*s2;
    LDS_RD10
    DECLP(a) CSTAGE(U, r, a)
    #define MQ4(i) { s.x += (float)(i)*(a##i.x*a##i.x + a##i.y*a##i.y); \
                     s.y += (float)(i)*(a##i.z*a##i.z + a##i.w*a##i.w); }
    MQ4(1) MQ4(2) MQ4(3) MQ4(4) MQ4(5) MQ4(6) MQ4(7) MQ4(8) MQ4(9)
    #undef MQ4
  }
  return s;
}

// Beamsplitter: photon-number-conserving anti-diagonal blocks (unchanged).
#define BSTQ(r) if ((r) < sz){ S[wadr] = a##r; wadr += ds; }
#define BSTQ_ALL BSTQ(0) BSTQ(1) BSTQ(2) BSTQ(3) BSTQ(4) BSTQ(5) BSTQ(6) BSTQ(7) BSTQ(8) BSTQ(9)
__device__ __forceinline__ void applyBS4(v4f* S, const cxf* __restrict__ BSp, int m1, int m2, int tid){
  int ra=-1, rb=-1;
  for (int q=0;q<4;q++) if (q!=m1 && q!=m2){ if (ra<0) ra=q; else rb=q; }
  const int sa0 = WS(ra), sb0 = WS(rb);
  const bool sw = (sa0==101 && sb0==10);
  const int sa = sw ? sb0 : sa0, sb = sw ? sa0 : sb0;
  const int s1 = WS(m1), s2 = WS(m2);
  const int ds = s1 - s2;
  #pragma unroll 1
  for (int w0=0; w0<2048; w0+=NTB){
    int it = w0 + tid;
    if (it < 1900){
      int bn = it/100, rest = it-100*bn;
      int ilo = bn<10?0:bn-9, ihi = bn<10?bn:9, sz = ihi-ilo+1;
      int ca = rest/10, cb = rest-10*ca;
      int base = ca*sa + cb*sb;
      const cxf* __restrict__ Bt = BSp + bn*100;   // transposed, zero-padded
      DECLP(a)
      int radr = base + ilo*s1 + (bn-ilo)*s2;
      int kk = 0;
      #pragma unroll 1
      for (int c=0;c<sz;c++){
        v4f rk = S[radr];
        CROWX(a, rk, (const v4f*)(Bt + kk))
        radr += ds; kk += 10;
      }
      int wadr = base + ilo*s1 + (bn-ilo)*s2;
      BSTQ_ALL
    }
  }
}

__global__ __launch_bounds__(NTB)
__attribute__((amdgpu_waves_per_eu(4)))
void state_kernel(const float* __restrict__ wd, const float* __restrict__ bd,
                  const float* __restrict__ wsf, float* __restrict__ out){
  extern __shared__ __align__(16) char smem[];
  v4f* S    = (v4f*)smem;                  // 10099 v4f (161584 B)
  cxf* uv   = (cxf*)(smem + 161584);       // 2 states * 4*10 encoding vectors
  v2f* red  = (v2f*)(smem + 162224);       // 16 waves

  const float* __restrict__ V   = wsf;            // for V^T gate
  const float* __restrict__ VT  = wsf + 100;      // for V gate
  const float* __restrict__ W   = wsf + 200;
  const cxf*   __restrict__ BSm = (const cxf*)(wsf + 1200);
  const cxf*   __restrict__ UL  = (const cxf*)(wsf + 5000);
  const cxf*   __restrict__ WU  = (const cxf*)(wsf + 9800);
  const cxf*   __restrict__ uw  = (const cxf*)(wsf + U_OFF);

  const int tid = threadIdx.x, wv = tid>>6, lane = tid&63;
  const int b = blockIdx.x;                // batch items 2b, 2b+1

  if (tid < 80) uv[tid] = uw[b*80 + tid];
  __syncthreads();

  // Init: both product states, interleaved {re0,im0,re1,im1}.
  for (int e=tid; e<10000; e+=NTB){
    int c0=e/1000, r_=e-1000*c0, c1=r_/100, r2_=r_-100*c1, c2=r2_/10, c3=r2_-10*c2;
    cxf A0 = uv[c0],    B0 = uv[10+c1], C0 = uv[20+c2], D0 = uv[30+c3];
    cxf A1 = uv[40+c0], B1 = uv[50+c1], C1 = uv[60+c2], D1 = uv[70+c3];
    float pr = A0.x*B0.x - A0.y*B0.y, pi = A0.x*B0.y + A0.y*B0.x;
    float qr = pr*C0.x - pi*C0.y,  qi = pr*C0.y + pi*C0.x;
    float e0r = qr*D0.x - qi*D0.y, e0i = qr*D0.y + qi*D0.x;
    pr = A1.x*B1.x - A1.y*B1.y; pi = A1.x*B1.y + A1.y*B1.x;
    qr = pr*C1.x - pi*C1.y;  qi = pr*C1.y + pi*C1.x;
    float e1r = qr*D1.x - qi*D1.y, e1i = qr*D1.y + qi*D1.x;
    S[c0*1010 + c1*101 + c2*10 + c3] = (v4f){e0r, e0i, e1r, e1i};
  }
  __syncthreads();

  // ---------------- Layer 0 (commutation-fused schedule) ----------------
  fuse_w1_r(S, W, V, tid);   __syncthreads();   // W(0,1) · V1^T
  fuse_w2_r(S, W, V, tid);   __syncthreads();   // W(0,2) · W(1,2) · V2^T
  fuse_w3_r(S, W, tid);      __syncthreads();   // W(0,3) · W(1,3) · W(2,3)
  apply1_r4(S, VT, 0, tid);  __syncthreads();   // V0
  apply1_r4(S, VT, 1, tid);  __syncthreads();   // V1
  apply1_r4(S, VT, 2, tid);  __syncthreads();   // V2
  applyBS4(S, BSm, 0, 1, tid); __syncthreads();
  applyBS4(S, BSm, 1, 2, tid); __syncthreads();
  applyBS4(S, BSm, 2, 3, tid); __syncthreads();
  applyBS4(S, BSm, 3, 0, tid); __syncthreads();
  apply1_c4(S, UL, 0, tid);  __syncthreads();   // UL0_L0 (carries L1's V0^T)

  // ---------------- Layer 1 ----------------
  fuse_w1_c(S, WU,        V, tid); __syncthreads();  // WU(1) · V1^T
  fuse_w2_c(S, WU + 1000, W, V, tid); __syncthreads();// WU(2) · W(1,2) · V2^T
  fuse_w3_c(S, WU + 2000, W, tid); __syncthreads();  // WU(3) · W(1,3) · W(2,3)
  apply1_r4(S, VT, 0, tid);  __syncthreads();   // V0
  apply1_r4(S, VT, 1, tid);  __syncthreads();   // V1
  apply1_r4(S, VT, 2, tid);  __syncthreads();   // V2
  applyBS4(S, BSm, 0, 1, tid); __syncthreads();
  applyBS4(S, BSm, 1, 2, tid); __syncthreads();
  applyBS4(S, BSm, 2, 3, tid); __syncthreads();
  applyBS4(S, BSm, 3, 0, tid); __syncthreads();

  // Fused measurement: UL[L1,m] applied read-only; UL[L1,3] dropped.
  float w0 = wd[0], w1 = wd[1], w2 = wd[2];
  v2f m0 = measure14(S, UL + 400, 0, tid);
  v2f m1 = measure14(S, UL + 500, 1, tid);
  v2f m2 = measure14(S, UL + 600, 2, tid);
  v2f acc;
  acc.x = w0*m0.x + w1*m1.x + w2*m2.x;
  acc.y = w0*m0.y + w1*m1.y + w2*m2.y;

  for (int off=32; off; off>>=1){
    acc.x += __shfl_down(acc.x, off, 64);
    acc.y += __shfl_down(acc.y, off, 64);
  }
  if (lane == 0) red[wv] = acc;
  __syncthreads();
  if (tid == 0){
    float sx = 0.f, sy = 0.f;
    for (int i=0;i<16;i++){ sx += red[i].x; sy += red[i].y; }
    out[2*b+0] = sx + bd[0];
    out[2*b+1] = sy + bd[0];
  }
}

} // anonymous namespace

extern "C" void kernel_launch(void* const* d_in, const int* in_sizes, int n_in,
                              void* d_out, int out_size, void* d_ws, size_t ws_size,
                              hipStream_t stream){
  const float* jets   = (const float*)d_in[0];
  const float* sscale = (const float*)d_in[1];
  const float* dmag   = (const float*)d_in[2];
  const float* dphase = (const float*)d_in[3];
  const float* smag   = (const float*)d_in[4];
  const float* sphase = (const float*)d_in[5];
  const float* wd     = (const float*)d_in[6];
  const float* bd     = (const float*)d_in[7];
  float* out = (float*)d_out;
  float* wsf = (float*)d_ws;
  int B = in_sizes[0] / 12;

  (void)hipFuncSetAttribute(reinterpret_cast<const void*>(&state_kernel),
                            hipFuncAttributeMaxDynamicSharedMemorySize, SMEM_STATE);

  gates_kernel<<<12, 256, 0, stream>>>(dmag, dphase, smag, sphase, wsf);
  fuse_kernel<<<1, 512, 0, stream>>>(wsf);
  enc_kernel<<<B*4, 128, 0, stream>>>(jets, sscale, wsf);
  state_kernel<<<B/2, NTB, SMEM_STATE, stream>>>(wd, bd, wsf, out);
}

// Round 10
// 821.483 us; speedup vs baseline: 1.1326x; 1.0296x over previous
//
#include <hip/hip_runtime.h>
#include <math.h>

// CV-photonic circuit: WIRES=4, LAYERS=2, CUTOFF=10, BATCH=2048.
// R23 = R22 (best: 660us state / 846 total; commutation-fused mega-passes,
//  2 batch-states v4f LDS, padded strides, hoisted b128, conflict swaps) +
//  aux-pipeline fixes:
//  (1) gates_kernel bisection: division-free Sturm (minor recurrence
//      p_k = -x p_{k-1} - (k-1) p_{k-2}, count sign changes == old q<0
//      count) and 52 iters — removes 800 serial double divides (~30us
//      of launch-chain latency ahead of everything).
//  (2) measure passes skip output row 0 (weighted by photon number 0):
//      -120 pk/thread across the 3 measures.

namespace {

constexpr int NTB = 1024;                 // threads per state block (16 waves)
constexpr int SMEM_STATE = 162352;        // 161584 state + 640 uv + 128 red
constexpr double THETA = 0.7853981633974483096; // pi/4

struct cxf { float x, y; };
typedef float v2f __attribute__((ext_vector_type(2)));
typedef float v4f __attribute__((ext_vector_type(4)));

// ws float layout:
// [0,100)       V    (V[k*10+m]; used directly for the V^T gate)
// [100,200)     VT   (VT[k*10+i] = V[i][k]; used for the V gate)
// [200,1200)    Wt   (10 real 10x10, transposed: Wt[n*100+k*10+i]=W_n[i][k])
// [1200,5000)   BSt  cxf[19*100] zero-padded, transposed
// [5000,6600)   ULt  cxf[8*100]: f=0 (L0 UL0, VT-folded), f=4,5,6 (measure)
// [6600,9800)   stage cxf[16*100] raw S_lay (0..7) / D_lay (8..15)
// [9800,15800)  WUt  cxf[30*100]: WU_{b}[n] transposed, id=(b-1)*10+n
// [15872,...)   u    cxf[B*4*10] encoded per-(b,w) vectors
constexpr int U_OFF = 15872;

__device__ __forceinline__ cxf gen_squeeze_f(int i, int j, float zr, float zi){
  if (j == i+2){ float g = 0.5f*sqrtf((float)((i+1)*(i+2))); return {zr*g, -zi*g}; }
  if (i == j+2){ float g = 0.5f*sqrtf((float)((j+1)*(j+2))); return {-zr*g, -zi*g}; }
  return {0.f, 0.f};
}
__device__ __forceinline__ cxf gen_disp_f(int i, int j, float ar, float ai){
  if (i == j+1){ float g = sqrtf((float)i); return {ar*g, ai*g}; }
  if (j == i+1){ float g = sqrtf((float)j); return {-ar*g, ai*g}; }
  return {0.f, 0.f};
}

// Wave-cooperative fixed-schedule fp32 expm: result = exp(M), n x n (n<=10).
__device__ void expm_f32(bool act, int n, cxf* M, cxf* P, cxf* T, cxf* R, int lane){
  const int n2 = n*n;
  if (act){
    for (int e=lane; e<n2; e+=64){ M[e].x *= 0x1p-10f; M[e].y *= 0x1p-10f; }
    for (int e=lane; e<n2; e+=64){
      P[e] = M[e];
      cxf r = M[e];
      if (e % (n+1) == 0) r.x += 1.f;
      R[e] = r;
    }
  }
  __syncthreads();
  for (int t=2; t<=12; ++t){
    if (act){
      float inv = 1.f/(float)t;
      for (int e=lane; e<n2; e+=64){
        int i = e/n, j = e - i*n;
        float ax=0.f, ay=0.f;
        for (int k=0;k<n;k++){
          cxf p = P[i*n+k], m = M[k*n+j];
          ax += p.x*m.x - p.y*m.y;
          ay += p.x*m.y + p.y*m.x;
        }
        T[e] = {ax*inv, ay*inv};
      }
    }
    __syncthreads();
    { cxf* tmp = P; P = T; T = tmp; }
    if (act){ for (int e=lane; e<n2; e+=64){ R[e].x += P[e].x; R[e].y += P[e].y; } }
    __syncthreads();
  }
  for (int s=0; s<10; ++s){
    if (act){
      for (int e=lane; e<n2; e+=64){
        int i = e/n, j = e - i*n;
        float ax=0.f, ay=0.f;
        for (int k=0;k<n;k++){
          cxf p = R[i*n+k], q = R[k*n+j];
          ax += p.x*q.x - p.y*q.y;
          ay += p.x*q.y + p.y*q.x;
        }
        T[e] = {ax, ay};
      }
    }
    __syncthreads();
    { cxf* tmp = R; R = T; T = tmp; }
    __syncthreads();
  }
}

// ------------- Kernel A: 45 expm tasks fully parallel over 12 blocks -------
__global__ __launch_bounds__(256)
void gates_kernel(const float* __restrict__ dmag, const float* __restrict__ dphase,
                  const float* __restrict__ smag, const float* __restrict__ sphase,
                  float* __restrict__ wsf){
  __shared__ double lam[10];
  __shared__ float scr[4][4][200];      // [wave][buf] cxf[100]
  const int tid = threadIdx.x;
  const int wv = tid >> 6, lane = tid & 63, g = blockIdx.x;
  float* ws_V  = wsf;
  float* ws_VT = wsf + 100;
  float* ws_W  = wsf + 200;
  cxf* ws_BS   = (cxf*)(wsf + 1200);
  cxf* ws_stage= (cxf*)(wsf + 6600);

  if (tid < 10){
    // Division-free Sturm bisection: count sign changes of the leading
    // principal minors p_k = -x p_{k-1} - (k-1) p_{k-2} (== old q<0 count).
    double lo = -6.0, hi = 6.0;
    for (int it=0; it<52; ++it){
      double mid = 0.5*(lo+hi);
      int cnt = 0;
      double pm1 = 1.0;                 // p_0
      double p = -mid;                  // p_1
      if (p == 0.0){ p = -1e-300; }
      if (p < 0.0) cnt++;
      for (int k=2; k<=10; ++k){
        double pn = -mid*p - (double)(k-1)*pm1;
        bool chg = (pn < 0.0) != (p < 0.0);
        if (pn == 0.0){ pn = (p < 0.0) ? 1e-300 : -1e-300; chg = true; }
        if (chg) cnt++;
        pm1 = p; p = pn;
      }
      if (cnt > tid) hi = mid; else lo = mid;
    }
    double x = 0.5*(lo+hi);
    double p[10];
    p[0] = 1.0; p[1] = x;
    for (int k=1;k<9;k++) p[k+1] = (x*p[k] - sqrt((double)k)*p[k-1]) * (1.0/sqrt((double)(k+1)));
    double nn=0.0; for (int k=0;k<10;k++) nn += p[k]*p[k];
    double inv = 1.0/sqrt(nn);
    lam[tid] = x;
    if (g == 0){
      for (int k=0;k<10;k++){
        float v = (float)(p[k]*inv);
        ws_V[k*10+tid]  = v;
        ws_VT[tid*10+k] = v;
      }
    }
  }
  __syncthreads();

  int t = g*4 + wv;
  bool act = (t < 45);
  int n = 10, bn = 0, ilo = 0;
  if (act && t >= 10 && t < 29){
    bn = t - 10; ilo = bn < 10 ? 0 : bn - 9;
    int ihi = bn < 10 ? bn : 9;
    n = ihi - ilo + 1;
  }
  cxf* M = (cxf*)scr[wv][0];
  cxf* P = (cxf*)scr[wv][1];
  cxf* T = (cxf*)scr[wv][2];
  cxf* R = (cxf*)scr[wv][3];
  if (act){
    if (t < 10){
      float l = (float)lam[t];   // Q = -0.5*(a - ad)
      for (int e=lane; e<100; e+=64){
        int i=e/10, j=e-10*i;
        float v = 0.f;
        if (j == i+1) v = -0.5f*l*sqrtf((float)(i+1));
        else if (i == j+1) v = 0.5f*l*sqrtf((float)i);
        M[e] = {v, 0.f};
      }
    } else if (t < 29){
      for (int e=lane; e<n*n; e+=64){
        int rr=e/n, c=e-n*rr;
        float v = 0.f;
        if (c == rr+1) v = (float)THETA*sqrtf((float)((ilo+rr+1)*(bn-ilo-rr)));
        else if (rr == c+1) v = (float)THETA*sqrtf((float)((ilo+c+1)*(bn-ilo-c)));
        M[e] = {0.f, v};
      }
    } else {
      int idx = t-29, kind = idx>>3, L=(idx>>2)&1, w=idx&3;
      float r_ = kind ? dmag[L*4+w]   : smag[L*4+w];
      float ph = kind ? dphase[L*4+w] : sphase[L*4+w];
      float zr = r_*cosf(ph), zi = r_*sinf(ph);
      for (int e=lane; e<100; e+=64){
        int i=e/10, j=e-10*i;
        M[e] = kind ? gen_disp_f(i,j,zr,zi) : gen_squeeze_f(i,j,zr,zi);
      }
    }
  }
  __syncthreads();
  expm_f32(act, n, M, P, T, R, lane);
  if (act){
    if (t < 10){
      for (int e=lane;e<100;e+=64){
        int i=e/10, j=e-10*i;
        ws_W[t*100 + j*10 + i] = R[e].x;   // transposed, real
      }
    } else if (t < 29){
      for (int e=lane;e<100;e+=64){
        int rr=e/10, c=e-10*rr;
        cxf o; o.x=0.f; o.y=0.f;
        if (rr < n && c < n) o = R[rr*n+c];
        ws_BS[bn*100 + c*10 + rr] = o;     // zero-padded + transposed
      }
    } else {
      int idx = t-29;
      for (int e=lane;e<100;e+=64) ws_stage[idx*100 + e] = R[e];
    }
  }
}

// ---- Kernel A2: UL products, VT fold, and WU_b[n] = W_n * UL_b fusion -----
__global__ __launch_bounds__(512)
void fuse_kernel(float* __restrict__ wsf){
  __shared__ cxf ulraw[8][100];          // raw UL[f] = D*S, [i*10+j]
  const int tid = threadIdx.x, wv = tid>>6, lane = tid&63;
  const cxf* stage = (const cxf*)(wsf + 6600);
  cxf* ws_UL = (cxf*)(wsf + 5000);
  cxf* ws_WU = (cxf*)(wsf + 9800);
  const float* V  = wsf;
  const float* Wt = wsf + 200;
  const cxf* Sm = stage + wv*100;
  const cxf* Dm = stage + (8+wv)*100;
  for (int e=lane; e<100; e+=64){
    int i=e/10, j=e-10*i;
    float ax=0.f, ay=0.f;
    for (int k=0;k<10;k++){
      cxf d=Dm[i*10+k], s=Sm[k*10+j];
      ax += d.x*s.x - d.y*s.y;
      ay += d.x*s.y + d.y*s.x;
    }
    ulraw[wv][e] = {ax, ay};
  }
  __syncthreads();
  // f=0 only: UL0 <- V^T * UL0 (carries L1's V0^T). Two elems per lane.
  cxf t0={0.f,0.f}, t1={0.f,0.f};
  if (wv == 0){
    {
      int e=lane, i=e/10, j=e-10*i;
      float ox=0.f, oy=0.f;
      for (int k=0;k<10;k++){ float v=V[k*10+i]; ox+=v*ulraw[0][k*10+j].x; oy+=v*ulraw[0][k*10+j].y; }
      t0 = {ox, oy};
    }
    if (lane+64 < 100){
      int e=lane+64, i=e/10, j=e-10*i;
      float ox=0.f, oy=0.f;
      for (int k=0;k<10;k++){ float v=V[k*10+i]; ox+=v*ulraw[0][k*10+j].x; oy+=v*ulraw[0][k*10+j].y; }
      t1 = {ox, oy};
    }
  }
  __syncthreads();
  if (wv == 0){
    ulraw[0][lane] = t0;
    if (lane+64 < 100) ulraw[0][lane+64] = t1;
  }
  __syncthreads();
  // Export ULt (transposed) for f in {0,4,5,6}
  for (int e=tid; e<400; e+=512){
    int fi = e/100, r = e-100*fi;
    int f = (fi==0) ? 0 : (3+fi);        // 0,4,5,6
    int i=r/10, j=r-10*i;
    ws_UL[f*100 + j*10 + i] = ulraw[f][i*10+j];
  }
  // Phase 2: WU_b[n] = W_n * ulraw[b], id=(b-1)*10+n, 30 tasks over 8 waves.
  for (int round=0; round<4; ++round){
    int id = round*8 + wv;
    if (id < 30){
      int b = 1 + id/10, n = id - (id/10)*10;
      const cxf* Ub = ulraw[b];
      for (int e=lane; e<100; e+=64){
        int i=e/10, j=e-10*i;
        float ax=0.f, ay=0.f;
        for (int k=0;k<10;k++){
          float w = Wt[n*100 + k*10 + i];   // W_n[i][k]
          ax += w*Ub[k*10+j].x;
          ay += w*Ub[k*10+j].y;
        }
        cxf o; o.x=ax; o.y=ay;
        ws_WU[id*100 + j*10 + i] = o;       // transposed
      }
    }
  }
}

// ------------- Kernel B: per-(b,w) encoding vector u = D*(S*e0), fp32 ------
__global__ __launch_bounds__(128)
void enc_kernel(const float* __restrict__ jets, const float* __restrict__ sscale,
                float* __restrict__ wsf){
  __shared__ float scr[2][4][200];
  __shared__ cxf col[10];
  __shared__ cxf uacc[10];
  const int tid = threadIdx.x, wv = tid>>6, lane = tid&63;
  const int blk = blockIdx.x, b = blk>>2, w = blk&3;

  float eta = jets[b*12 + w*3 + 0];
  float jph = jets[b*12 + w*3 + 1];
  float pt  = jets[b*12 + w*3 + 2];

  cxf* M = (cxf*)scr[wv][0];
  cxf* P = (cxf*)scr[wv][1];
  cxf* T = (cxf*)scr[wv][2];
  cxf* R = (cxf*)scr[wv][3];
  {
    float zr, zi;
    if (wv == 0){ float phs = pt*jph*0.5f; zr = eta*cosf(phs); zi = eta*sinf(phs); }
    else {
      double sc = 10.0/(1.0 + exp(-(double)sscale[0])) + 0.01;
      float mag = (float)sc*pt; zr = mag*cosf(eta); zi = mag*sinf(eta);
    }
    for (int e=lane; e<100; e+=64){
      int i=e/10, j=e-10*i;
      M[e] = wv ? gen_disp_f(i,j,zr,zi) : gen_squeeze_f(i,j,zr,zi);
    }
  }
  __syncthreads();
  expm_f32(true, 10, M, P, T, R, lane);
  cxf* Rs = (cxf*)scr[0][3];
  cxf* Rd = (cxf*)scr[1][3];
  if (tid < 10) col[tid] = Rs[tid*10];           // squeeze column 0
  __syncthreads();
  if (tid < 10){
    float ax=0.f, ay=0.f;
    for (int k=0;k<10;k++){
      cxf d = Rd[tid*10+k], c = col[k];
      ax += d.x*c.x - d.y*c.y;
      ay += d.x*c.y + d.y*c.x;
    }
    uacc[tid] = {ax, ay};
  }
  __syncthreads();
  if (tid < 10){
    float rx, ry;
    if (w == 0){
      rx = 0.f; ry = 0.f;
      for (int k=0;k<10;k++){
        float v = wsf[k*10 + tid];               // (V^T)[tid][k]
        rx += v*uacc[k].x;
        ry += v*uacc[k].y;
      }
    } else { rx = uacc[tid].x; ry = uacc[tid].y; }
    float* u_out = wsf + U_OFF + (b*40 + w*10 + tid)*2;
    u_out[0] = rx;
    u_out[1] = ry;
  }
}

// ---------------- Kernel C: the circuit, 2 states/block, v4f LDS -----------
// Padded digit strides: element (c0,c1,c2,c3) -> c0*1010 + c1*101 + c2*10 + c3.
__device__ __forceinline__ constexpr int WS(int w){
  return w==0 ? 1010 : (w==1 ? 101 : (w==2 ? 10 : 1));
}

// ---- generic chained-stage building blocks (prefix-named register sets) ----
#define DECLP(P) v4f P##0={0.f,0.f,0.f,0.f}, P##1=P##0, P##2=P##0, P##3=P##0, \
  P##4=P##0, P##5=P##0, P##6=P##0, P##7=P##0, P##8=P##0, P##9=P##0;

#define REX(O,i,u) O##i = __builtin_elementwise_fma((v4f){(u),(u),(u),(u)}, vv, O##i);

#define RPAIRX(O, va, vb, Mp_) { \
  const v4f* Mp = (Mp_); \
  v4f q0=Mp[0],q1=Mp[1],q2=Mp[2],q3=Mp[3],q4=Mp[4]; \
  { v4f vv=va; REX(O,0,q0.x) REX(O,1,q0.y) REX(O,2,q0.z) REX(O,3,q0.w) REX(O,4,q1.x) \
               REX(O,5,q1.y) REX(O,6,q1.z) REX(O,7,q1.w) REX(O,8,q2.x) REX(O,9,q2.y) } \
  { v4f vv=vb; REX(O,0,q2.z) REX(O,1,q2.w) REX(O,2,q3.x) REX(O,3,q3.y) REX(O,4,q3.z) \
               REX(O,5,q3.w) REX(O,6,q4.x) REX(O,7,q4.y) REX(O,8,q4.z) REX(O,9,q4.w) } }

#define RSTAGE(Mt, I, O) \
  RPAIRX(O, I##0, I##1, (const v4f*)((Mt)+0))  \
  RPAIRX(O, I##2, I##3, (const v4f*)((Mt)+20)) \
  RPAIRX(O, I##4, I##5, (const v4f*)((Mt)+40)) \
  RPAIRX(O, I##6, I##7, (const v4f*)((Mt)+60)) \
  RPAIRX(O, I##8, I##9, (const v4f*)((Mt)+80))

#define CEX(O,i,ur,ui) \
  O##i = __builtin_elementwise_fma((v4f){(ur),(ur),(ur),(ur)}, vv, O##i); \
  O##i = __builtin_elementwise_fma((v4f){-(ui),(ui),-(ui),(ui)}, vs, O##i);

#define CROWX(O, vk, Up_) { \
  const v4f* Up = (Up_); \
  v4f q0=Up[0],q1=Up[1],q2=Up[2],q3=Up[3],q4=Up[4]; \
  v4f vv=vk, vs=__builtin_shufflevector(vk,vk,1,0,3,2); \
  CEX(O,0,q0.x,q0.y) CEX(O,1,q0.z,q0.w) CEX(O,2,q1.x,q1.y) CEX(O,3,q1.z,q1.w) \
  CEX(O,4,q2.x,q2.y) CEX(O,5,q2.z,q2.w) CEX(O,6,q3.x,q3.y) CEX(O,7,q3.z,q3.w) \
  CEX(O,8,q4.x,q4.y) CEX(O,9,q4.z,q4.w) }

// measure variant: output row 0 (photon number 0, weight 0) skipped.
#define CROWX9(O, vk, Up_) { \
  const v4f* Up = (Up_); \
  v4f q0=Up[0],q1=Up[1],q2=Up[2],q3=Up[3],q4=Up[4]; \
  v4f vv=vk, vs=__builtin_shufflevector(vk,vk,1,0,3,2); \
  CEX(O,1,q0.z,q0.w) CEX(O,2,q1.x,q1.y) CEX(O,3,q1.z,q1.w) \
  CEX(O,4,q2.x,q2.y) CEX(O,5,q2.z,q2.w) CEX(O,6,q3.x,q3.y) CEX(O,7,q3.z,q3.w) \
  CEX(O,8,q4.x,q4.y) CEX(O,9,q4.z,q4.w) }

#define CSTAGE(U, I, O) \
  CROWX(O, I##0, (const v4f*)((U)+0))  CROWX(O, I##1, (const v4f*)((U)+10)) \
  CROWX(O, I##2, (const v4f*)((U)+20)) CROWX(O, I##3, (const v4f*)((U)+30)) \
  CROWX(O, I##4, (const v4f*)((U)+40)) CROWX(O, I##5, (const v4f*)((U)+50)) \
  CROWX(O, I##6, (const v4f*)((U)+60)) CROWX(O, I##7, (const v4f*)((U)+70)) \
  CROWX(O, I##8, (const v4f*)((U)+80)) CROWX(O, I##9, (const v4f*)((U)+90))

#define CSTAGE9(U, I, O) \
  CROWX9(O, I##0, (const v4f*)((U)+0))  CROWX9(O, I##1, (const v4f*)((U)+10)) \
  CROWX9(O, I##2, (const v4f*)((U)+20)) CROWX9(O, I##3, (const v4f*)((U)+30)) \
  CROWX9(O, I##4, (const v4f*)((U)+40)) CROWX9(O, I##5, (const v4f*)((U)+50)) \
  CROWX9(O, I##6, (const v4f*)((U)+60)) CROWX9(O, I##7, (const v4f*)((U)+70)) \
  CROWX9(O, I##8, (const v4f*)((U)+80)) CROWX9(O, I##9, (const v4f*)((U)+90))

#define LDS_RD10 \
  v4f r0=S[base], r1=S[base+sm], r2=S[base+2*sm], r3=S[base+3*sm], r4=S[base+4*sm], \
      r5=S[base+5*sm], r6=S[base+6*sm], r7=S[base+7*sm], r8=S[base+8*sm], r9=S[base+9*sm];

#define PSTORE10(P) { S[base]=P##0; S[base+sm]=P##1; S[base+2*sm]=P##2; S[base+3*sm]=P##3; \
  S[base+4*sm]=P##4; S[base+5*sm]=P##5; S[base+6*sm]=P##6; S[base+7*sm]=P##7; \
  S[base+8*sm]=P##8; S[base+9*sm]=P##9; }

// ---- fused mega-passes -----------------------------------------------------
// w1: [W(0,1) cond c0] -> [V1^T uniform].  fiber (c0,c2,c3), act stride 101.
__device__ __forceinline__ void fuse_w1_r(v4f* S, const float* __restrict__ Wall,
                                          const float* __restrict__ Mu, int tid){
  if (tid < 1000){
    int d0=tid/100, rem=tid-100*d0, d1=rem/10, d2=rem-10*d1;
    const int sm = 101;
    int base = d0*1010 + d1*10 + d2;
    LDS_RD10
    const float* M1 = Wall + d0*100;
    DECLP(a) RSTAGE(M1, r, a)
    DECLP(b) RSTAGE(Mu, a, b)
    PSTORE10(b)
  }
}
// L1 variant: stage1 complex WU(1).
__device__ __forceinline__ void fuse_w1_c(v4f* S, const cxf* __restrict__ WUb,
                                          const float* __restrict__ Mu, int tid){
  if (tid < 1000){
    int d0=tid/100, rem=tid-100*d0, d1=rem/10, d2=rem-10*d1;
    const int sm = 101;
    int base = d0*1010 + d1*10 + d2;
    LDS_RD10
    const cxf* U1 = WUb + d0*100;
    DECLP(a) CSTAGE(U1, r, a)
    DECLP(b) RSTAGE(Mu, a, b)
    PSTORE10(b)
  }
}
// w2: [W(0,2) c0] -> [W(1,2) c1] -> [V2^T].  fiber (c0,c1,c3), act stride 10.
__device__ __forceinline__ void fuse_w2_r(v4f* S, const float* __restrict__ Wall,
                                          const float* __restrict__ Mu, int tid){
  if (tid < 1000){
    int d0=tid/100, rem=tid-100*d0, d1=rem/10, d2=rem-10*d1;
    const int sm = 10;
    int base = d0*1010 + d1*101 + d2;
    LDS_RD10
    const float* M1 = Wall + d0*100;
    const float* M2 = Wall + d1*100;
    DECLP(a) RSTAGE(M1, r, a)
    DECLP(b) RSTAGE(M2, a, b)
    DECLP(c) RSTAGE(Mu, b, c)
    PSTORE10(c)
  }
}
__device__ __forceinline__ void fuse_w2_c(v4f* S, const cxf* __restrict__ WUb,
                                          const float* __restrict__ Wall,
                                          const float* __restrict__ Mu, int tid){
  if (tid < 1000){
    int d0=tid/100, rem=tid-100*d0, d1=rem/10, d2=rem-10*d1;
    const int sm = 10;
    int base = d0*1010 + d1*101 + d2;
    LDS_RD10
    const cxf* U1 = WUb + d0*100;
    const float* M2 = Wall + d1*100;
    DECLP(a) CSTAGE(U1, r, a)
    DECLP(b) RSTAGE(M2, a, b)
    DECLP(c) RSTAGE(Mu, b, c)
    PSTORE10(c)
  }
}
// w3: [W(0,3) c0] -> [W(1,3) c1] -> [W(2,3) c2].  fiber (c0,c1=d2,c2=d1),
// act stride 1; d2 on stride 101 keeps b128 conflict-free (R21 swap).
__device__ __forceinline__ void fuse_w3_r(v4f* S, const float* __restrict__ Wall, int tid){
  if (tid < 1000){
    int d0=tid/100, rem=tid-100*d0, d1=rem/10, d2=rem-10*d1;
    const int sm = 1;
    int base = d0*1010 + d2*101 + d1*10;
    LDS_RD10
    const float* M1 = Wall + d0*100;     // cond c0
    const float* M2 = Wall + d2*100;     // cond c1
    const float* M3 = Wall + d1*100;     // cond c2
    DECLP(a) RSTAGE(M1, r, a)
    DECLP(b) RSTAGE(M2, a, b)
    DECLP(c) RSTAGE(M3, b, c)
    PSTORE10(c)
  }
}
__device__ __forceinline__ void fuse_w3_c(v4f* S, const cxf* __restrict__ WUb,
                                          const float* __restrict__ Wall, int tid){
  if (tid < 1000){
    int d0=tid/100, rem=tid-100*d0, d1=rem/10, d2=rem-10*d1;
    const int sm = 1;
    int base = d0*1010 + d2*101 + d1*10;
    LDS_RD10
    const cxf* U1 = WUb + d0*100;        // cond c0 (complex)
    const float* M2 = Wall + d2*100;     // cond c1
    const float* M3 = Wall + d1*100;     // cond c2
    DECLP(a) CSTAGE(U1, r, a)
    DECLP(b) RSTAGE(M2, a, b)
    DECLP(c) RSTAGE(M3, b, c)
    PSTORE10(c)
  }
}

// ---- uniform single-wire passes -------------------------------------------
__device__ __forceinline__ void apply1_r4(v4f* S, const float* __restrict__ Mt, int m, int tid){
  const int sm = WS(m);
  const int x0 = (m==0)?1:0, x1=(m<=1)?2:1, x2=(m<=2)?3:2;
  const int s0 = WS(x0), s1 = WS(x1), s2 = WS(x2);
  if (tid < 1000){
    int d0=tid/100, rem=tid-100*d0, d1=rem/10, d2=rem-10*d1;
    int base = d0*s0 + d1*s1 + d2*s2;
    LDS_RD10
    DECLP(a) RSTAGE(Mt, r, a)
    PSTORE10(a)
  }
}

__device__ __forceinline__ void apply1_c4(v4f* S, const cxf* __restrict__ U, int m, int tid){
  const int sm = WS(m);
  const int x0 = (m==0)?1:0, x1=(m<=1)?2:1, x2=(m<=2)?3:2;
  const int s0 = WS(x0), s1 = WS(x1), s2 = WS(x2);
  if (tid < 1000){
    int d0=tid/100, rem=tid-100*d0, d1=rem/10, d2=rem-10*d1;
    int base = d0*s0 + d1*s1 + d2*s2;
    LDS_RD10
    DECLP(a) CSTAGE(U, r, a)
    PSTORE10(a)
  }
}

// Read-only measure: per-state sum_i i*|(U v)_i|^2 over this thread's fiber.
// Output row 0 skipped (weight 0).
__device__ __forceinline__ v2f measure14(const v4f* S, const cxf* __restrict__ U, int m, int tid){
  const int sm = WS(m);
  const int x0 = (m==0)?1:0, x1=(m<=1)?2:1, x2=3;
  const int s0 = WS(x0), s1 = WS(x1), s2 = WS(x2);
  v2f s = {0.f, 0.f};
  if (tid < 1000){
    int d0=tid/100, rem=tid-100*d0, d1=rem/10, d2=rem-10*d1;
    int base = d0*s0 + d1*s1 + d2*s2;
    LDS_RD10
    DECLP(a) CSTAGE9(U, r, a)
    #define MQ4(i) { s.x += (float)(i)*(a##i.x*a##i.x + a##i.y*a##i.y); \
                     s.y += (float)(i)*(a##i.z*a##i.z + a##i.w*a##i.w); }
    MQ4(1) MQ4(2) MQ4(3) MQ4(4) MQ4(5) MQ4(6) MQ4(7) MQ4(8) MQ4(9)
    #undef MQ4
  }
  return s;
}

// Beamsplitter: photon-number-conserving anti-diagonal blocks (unchanged).
#define BSTQ(r) if ((r) < sz){ S[wadr] = a##r; wadr += ds; }
#define BSTQ_ALL BSTQ(0) BSTQ(1) BSTQ(2) BSTQ(3) BSTQ(4) BSTQ(5) BSTQ(6) BSTQ(7) BSTQ(8) BSTQ(9)
__device__ __forceinline__ void applyBS4(v4f* S, const cxf* __restrict__ BSp, int m1, int m2, int tid){
  int ra=-1, rb=-1;
  for (int q=0;q<4;q++) if (q!=m1 && q!=m2){ if (ra<0) ra=q; else rb=q; }
  const int sa0 = WS(ra), sb0 = WS(rb);
  const bool sw = (sa0==101 && sb0==10);
  const int sa = sw ? sb0 : sa0, sb = sw ? sa0 : sb0;
  const int s1 = WS(m1), s2 = WS(m2);
  const int ds = s1 - s2;
  #pragma unroll 1
  for (int w0=0; w0<2048; w0+=NTB){
    int it = w0 + tid;
    if (it < 1900){
      int bn = it/100, rest = it-100*bn;
      int ilo = bn<10?0:bn-9, ihi = bn<10?bn:9, sz = ihi-ilo+1;
      int ca = rest/10, cb = rest-10*ca;
      int base = ca*sa + cb*sb;
      const cxf* __restrict__ Bt = BSp + bn*100;   // transposed, zero-padded
      DECLP(a)
      int radr = base + ilo*s1 + (bn-ilo)*s2;
      int kk = 0;
      #pragma unroll 1
      for (int c=0;c<sz;c++){
        v4f rk = S[radr];
        CROWX(a, rk, (const v4f*)(Bt + kk))
        radr += ds; kk += 10;
      }
      int wadr = base + ilo*s1 + (bn-ilo)*s2;
      BSTQ_ALL
    }
  }
}

__global__ __launch_bounds__(NTB)
__attribute__((amdgpu_waves_per_eu(4)))
void state_kernel(const float* __restrict__ wd, const float* __restrict__ bd,
                  const float* __restrict__ wsf, float* __restrict__ out){
  extern __shared__ __align__(16) char smem[];
  v4f* S    = (v4f*)smem;                  // 10099 v4f (161584 B)
  cxf* uv   = (cxf*)(smem + 161584);       // 2 states * 4*10 encoding vectors
  v2f* red  = (v2f*)(smem + 162224);       // 16 waves

  const float* __restrict__ V   = wsf;            // for V^T gate
  const float* __restrict__ VT  = wsf + 100;      // for V gate
  const float* __restrict__ W   = wsf + 200;
  const cxf*   __restrict__ BSm = (const cxf*)(wsf + 1200);
  const cxf*   __restrict__ UL  = (const cxf*)(wsf + 5000);
  const cxf*   __restrict__ WU  = (const cxf*)(wsf + 9800);
  const cxf*   __restrict__ uw  = (const cxf*)(wsf + U_OFF);

  const int tid = threadIdx.x, wv = tid>>6, lane = tid&63;
  const int b = blockIdx.x;                // batch items 2b, 2b+1

  if (tid < 80) uv[tid] = uw[b*80 + tid];
  __syncthreads();

  // Init: both product states, interleaved {re0,im0,re1,im1}.
  for (int e=tid; e<10000; e+=NTB){
    int c0=e/1000, r_=e-1000*c0, c1=r_/100, r2_=r_-100*c1, c2=r2_/10, c3=r2_-10*c2;
    cxf A0 = uv[c0],    B0 = uv[10+c1], C0 = uv[20+c2], D0 = uv[30+c3];
    cxf A1 = uv[40+c0], B1 = uv[50+c1], C1 = uv[60+c2], D1 = uv[70+c3];
    float pr = A0.x*B0.x - A0.y*B0.y, pi = A0.x*B0.y + A0.y*B0.x;
    float qr = pr*C0.x - pi*C0.y,  qi = pr*C0.y + pi*C0.x;
    float e0r = qr*D0.x - qi*D0.y, e0i = qr*D0.y + qi*D0.x;
    pr = A1.x*B1.x - A1.y*B1.y; pi = A1.x*B1.y + A1.y*B1.x;
    qr = pr*C1.x - pi*C1.y;  qi = pr*C1.y + pi*C1.x;
    float e1r = qr*D1.x - qi*D1.y, e1i = qr*D1.y + qi*D1.x;
    S[c0*1010 + c1*101 + c2*10 + c3] = (v4f){e0r, e0i, e1r, e1i};
  }
  __syncthreads();

  // ---------------- Layer 0 (commutation-fused schedule) ----------------
  fuse_w1_r(S, W, V, tid);   __syncthreads();   // W(0,1) · V1^T
  fuse_w2_r(S, W, V, tid);   __syncthreads();   // W(0,2) · W(1,2) · V2^T
  fuse_w3_r(S, W, tid);      __syncthreads();   // W(0,3) · W(1,3) · W(2,3)
  apply1_r4(S, VT, 0, tid);  __syncthreads();   // V0
  apply1_r4(S, VT, 1, tid);  __syncthreads();   // V1
  apply1_r4(S, VT, 2, tid);  __syncthreads();   // V2
  applyBS4(S, BSm, 0, 1, tid); __syncthreads();
  applyBS4(S, BSm, 1, 2, tid); __syncthreads();
  applyBS4(S, BSm, 2, 3, tid); __syncthreads();
  applyBS4(S, BSm, 3, 0, tid); __syncthreads();
  apply1_c4(S, UL, 0, tid);  __syncthreads();   // UL0_L0 (carries L1's V0^T)

  // ---------------- Layer 1 ----------------
  fuse_w1_c(S, WU,        V, tid); __syncthreads();  // WU(1) · V1^T
  fuse_w2_c(S, WU + 1000, W, V, tid); __syncthreads();// WU(2) · W(1,2) · V2^T
  fuse_w3_c(S, WU + 2000, W, tid); __syncthreads();  // WU(3) · W(1,3) · W(2,3)
  apply1_r4(S, VT, 0, tid);  __syncthreads();   // V0
  apply1_r4(S, VT, 1, tid);  __syncthreads();   // V1
  apply1_r4(S, VT, 2, tid);  __syncthreads();   // V2
  applyBS4(S, BSm, 0, 1, tid); __syncthreads();
  applyBS4(S, BSm, 1, 2, tid); __syncthreads();
  applyBS4(S, BSm, 2, 3, tid); __syncthreads();
  applyBS4(S, BSm, 3, 0, tid); __syncthreads();

  // Fused measurement: UL[L1,m] applied read-only; UL[L1,3] dropped.
  float w0 = wd[0], w1 = wd[1], w2 = wd[2];
  v2f m0 = measure14(S, UL + 400, 0, tid);
  v2f m1 = measure14(S, UL + 500, 1, tid);
  v2f m2 = measure14(S, UL + 600, 2, tid);
  v2f acc;
  acc.x = w0*m0.x + w1*m1.x + w2*m2.x;
  acc.y = w0*m0.y + w1*m1.y + w2*m2.y;

  for (int off=32; off; off>>=1){
    acc.x += __shfl_down(acc.x, off, 64);
    acc.y += __shfl_down(acc.y, off, 64);
  }
  if (lane == 0) red[wv] = acc;
  __syncthreads();
  if (tid == 0){
    float sx = 0.f, sy = 0.f;
    for (int i=0;i<16;i++){ sx += red[i].x; sy += red[i].y; }
    out[2*b+0] = sx + bd[0];
    out[2*b+1] = sy + bd[0];
  }
}

} // anonymous namespace

extern "C" void kernel_launch(void* const* d_in, const int* in_sizes, int n_in,
                              void* d_out, int out_size, void* d_ws, size_t ws_size,
                              hipStream_t stream){
  const float* jets   = (const float*)d_in[0];
  const float* sscale = (const float*)d_in[1];
  const float* dmag   = (const float*)d_in[2];
  const float* dphase = (const float*)d_in[3];
  const float* smag   = (const float*)d_in[4];
  const float* sphase = (const float*)d_in[5];
  const float* wd     = (const float*)d_in[6];
  const float* bd     = (const float*)d_in[7];
  float* out = (float*)d_out;
  float* wsf = (float*)d_ws;
  int B = in_sizes[0] / 12;

  (void)hipFuncSetAttribute(reinterpret_cast<const void*>(&state_kernel),
                            hipFuncAttributeMaxDynamicSharedMemorySize, SMEM_STATE);

  gates_kernel<<<12, 256, 0, stream>>>(dmag, dphase, smag, sphase, wsf);
  fuse_kernel<<<1, 512, 0, stream>>>(wsf);
  enc_kernel<<<B*4, 128, 0, stream>>>(jets, sscale, wsf);
  state_kernel<<<B/2, NTB, SMEM_STATE, stream>>>(wd, bd, wsf, out);
}

// Round 11
// 768.499 us; speedup vs baseline: 1.2107x; 1.0689x over previous
//
#include <hip/hip_runtime.h>
#include <math.h>

// CV-photonic circuit: WIRES=4, LAYERS=2, CUTOFF=10, BATCH=2048.
// R24 = R23 aux kernels + state_kernel rebuilt on the R21 (unfused)
//  schedule with WAVE-UNIFORM conditioning:
//  Cost model from R21/R22 simultaneous eqns: per-pass fixed cost F~1.1K cy
//  (barriers cheap), Work~370K cy/gen of which only ~125K is VALU. The
//  rest tracks divergent matrix dwordx4 loads (vmem pipe ~16cy/wave-load).
//  Fix: conditional passes remapped to 20 tasks (d0 x half), one task per
//  wave (50 lanes), d0 via readfirstlane -> matrix pointer uniform ->
//  s_load (scalar cache, no vector-pipe cost). BS: 38 (bn,half) tasks,
//  bn uniform (sz-loop uniform too). Rounds within a pass are disjoint
//  (different d0 / bn) -> no internal barriers. Unfusing adds ~10 passes
//  at ~1.1K cy each — cheap. V/UL/measure already uniform-address.

namespace {

constexpr int NTB = 1024;                 // threads per state block (16 waves)
constexpr int SMEM_STATE = 162352;        // 161584 state + 640 uv + 128 red
constexpr double THETA = 0.7853981633974483096; // pi/4

struct cxf { float x, y; };
typedef float v2f __attribute__((ext_vector_type(2)));
typedef float v4f __attribute__((ext_vector_type(4)));

// ws float layout:
// [0,100)       V    (V[k*10+m]; used directly for the V^T gate)
// [100,200)     VT   (VT[k*10+i] = V[i][k]; used for the V gate)
// [200,1200)    Wt   (10 real 10x10, transposed: Wt[n*100+k*10+i]=W_n[i][k])
// [1200,5000)   BSt  cxf[19*100] zero-padded, transposed
// [5000,6600)   ULt  cxf[8*100]: f=0 (L0 UL0, VT-folded), f=4,5,6 (measure)
// [6600,9800)   stage cxf[16*100] raw S_lay (0..7) / D_lay (8..15)
// [9800,15800)  WUt  cxf[30*100]: WU_{b}[n] transposed, id=(b-1)*10+n
// [15872,...)   u    cxf[B*4*10] encoded per-(b,w) vectors
constexpr int U_OFF = 15872;

__device__ __forceinline__ cxf gen_squeeze_f(int i, int j, float zr, float zi){
  if (j == i+2){ float g = 0.5f*sqrtf((float)((i+1)*(i+2))); return {zr*g, -zi*g}; }
  if (i == j+2){ float g = 0.5f*sqrtf((float)((j+1)*(j+2))); return {-zr*g, -zi*g}; }
  return {0.f, 0.f};
}
__device__ __forceinline__ cxf gen_disp_f(int i, int j, float ar, float ai){
  if (i == j+1){ float g = sqrtf((float)i); return {ar*g, ai*g}; }
  if (j == i+1){ float g = sqrtf((float)j); return {-ar*g, ai*g}; }
  return {0.f, 0.f};
}

// Wave-cooperative fixed-schedule fp32 expm: result = exp(M), n x n (n<=10).
__device__ void expm_f32(bool act, int n, cxf* M, cxf* P, cxf* T, cxf* R, int lane){
  const int n2 = n*n;
  if (act){
    for (int e=lane; e<n2; e+=64){ M[e].x *= 0x1p-10f; M[e].y *= 0x1p-10f; }
    for (int e=lane; e<n2; e+=64){
      P[e] = M[e];
      cxf r = M[e];
      if (e % (n+1) == 0) r.x += 1.f;
      R[e] = r;
    }
  }
  __syncthreads();
  for (int t=2; t<=12; ++t){
    if (act){
      float inv = 1.f/(float)t;
      for (int e=lane; e<n2; e+=64){
        int i = e/n, j = e - i*n;
        float ax=0.f, ay=0.f;
        for (int k=0;k<n;k++){
          cxf p = P[i*n+k], m = M[k*n+j];
          ax += p.x*m.x - p.y*m.y;
          ay += p.x*m.y + p.y*m.x;
        }
        T[e] = {ax*inv, ay*inv};
      }
    }
    __syncthreads();
    { cxf* tmp = P; P = T; T = tmp; }
    if (act){ for (int e=lane; e<n2; e+=64){ R[e].x += P[e].x; R[e].y += P[e].y; } }
    __syncthreads();
  }
  for (int s=0; s<10; ++s){
    if (act){
      for (int e=lane; e<n2; e+=64){
        int i = e/n, j = e - i*n;
        float ax=0.f, ay=0.f;
        for (int k=0;k<n;k++){
          cxf p = R[i*n+k], q = R[k*n+j];
          ax += p.x*q.x - p.y*q.y;
          ay += p.x*q.y + p.y*q.x;
        }
        T[e] = {ax, ay};
      }
    }
    __syncthreads();
    { cxf* tmp = R; R = T; T = tmp; }
    __syncthreads();
  }
}

// ------------- Kernel A: 45 expm tasks fully parallel over 12 blocks -------
__global__ __launch_bounds__(256)
void gates_kernel(const float* __restrict__ dmag, const float* __restrict__ dphase,
                  const float* __restrict__ smag, const float* __restrict__ sphase,
                  float* __restrict__ wsf){
  __shared__ double lam[10];
  __shared__ float scr[4][4][200];      // [wave][buf] cxf[100]
  const int tid = threadIdx.x;
  const int wv = tid >> 6, lane = tid & 63, g = blockIdx.x;
  float* ws_V  = wsf;
  float* ws_VT = wsf + 100;
  float* ws_W  = wsf + 200;
  cxf* ws_BS   = (cxf*)(wsf + 1200);
  cxf* ws_stage= (cxf*)(wsf + 6600);

  if (tid < 10){
    // Division-free Sturm bisection (minor recurrence, sign changes).
    double lo = -6.0, hi = 6.0;
    for (int it=0; it<52; ++it){
      double mid = 0.5*(lo+hi);
      int cnt = 0;
      double pm1 = 1.0;                 // p_0
      double p = -mid;                  // p_1
      if (p == 0.0){ p = -1e-300; }
      if (p < 0.0) cnt++;
      for (int k=2; k<=10; ++k){
        double pn = -mid*p - (double)(k-1)*pm1;
        bool chg = (pn < 0.0) != (p < 0.0);
        if (pn == 0.0){ pn = (p < 0.0) ? 1e-300 : -1e-300; chg = true; }
        if (chg) cnt++;
        pm1 = p; p = pn;
      }
      if (cnt > tid) hi = mid; else lo = mid;
    }
    double x = 0.5*(lo+hi);
    double p[10];
    p[0] = 1.0; p[1] = x;
    for (int k=1;k<9;k++) p[k+1] = (x*p[k] - sqrt((double)k)*p[k-1]) * (1.0/sqrt((double)(k+1)));
    double nn=0.0; for (int k=0;k<10;k++) nn += p[k]*p[k];
    double inv = 1.0/sqrt(nn);
    lam[tid] = x;
    if (g == 0){
      for (int k=0;k<10;k++){
        float v = (float)(p[k]*inv);
        ws_V[k*10+tid]  = v;
        ws_VT[tid*10+k] = v;
      }
    }
  }
  __syncthreads();

  int t = g*4 + wv;
  bool act = (t < 45);
  int n = 10, bn = 0, ilo = 0;
  if (act && t >= 10 && t < 29){
    bn = t - 10; ilo = bn < 10 ? 0 : bn - 9;
    int ihi = bn < 10 ? bn : 9;
    n = ihi - ilo + 1;
  }
  cxf* M = (cxf*)scr[wv][0];
  cxf* P = (cxf*)scr[wv][1];
  cxf* T = (cxf*)scr[wv][2];
  cxf* R = (cxf*)scr[wv][3];
  if (act){
    if (t < 10){
      float l = (float)lam[t];   // Q = -0.5*(a - ad)
      for (int e=lane; e<100; e+=64){
        int i=e/10, j=e-10*i;
        float v = 0.f;
        if (j == i+1) v = -0.5f*l*sqrtf((float)(i+1));
        else if (i == j+1) v = 0.5f*l*sqrtf((float)i);
        M[e] = {v, 0.f};
      }
    } else if (t < 29){
      for (int e=lane; e<n*n; e+=64){
        int rr=e/n, c=e-n*rr;
        float v = 0.f;
        if (c == rr+1) v = (float)THETA*sqrtf((float)((ilo+rr+1)*(bn-ilo-rr)));
        else if (rr == c+1) v = (float)THETA*sqrtf((float)((ilo+c+1)*(bn-ilo-c)));
        M[e] = {0.f, v};
      }
    } else {
      int idx = t-29, kind = idx>>3, L=(idx>>2)&1, w=idx&3;
      float r_ = kind ? dmag[L*4+w]   : smag[L*4+w];
      float ph = kind ? dphase[L*4+w] : sphase[L*4+w];
      float zr = r_*cosf(ph), zi = r_*sinf(ph);
      for (int e=lane; e<100; e+=64){
        int i=e/10, j=e-10*i;
        M[e] = kind ? gen_disp_f(i,j,zr,zi) : gen_squeeze_f(i,j,zr,zi);
      }
    }
  }
  __syncthreads();
  expm_f32(act, n, M, P, T, R, lane);
  if (act){
    if (t < 10){
      for (int e=lane;e<100;e+=64){
        int i=e/10, j=e-10*i;
        ws_W[t*100 + j*10 + i] = R[e].x;   // transposed, real
      }
    } else if (t < 29){
      for (int e=lane;e<100;e+=64){
        int rr=e/10, c=e-10*rr;
        cxf o; o.x=0.f; o.y=0.f;
        if (rr < n && c < n) o = R[rr*n+c];
        ws_BS[bn*100 + c*10 + rr] = o;     // zero-padded + transposed
      }
    } else {
      int idx = t-29;
      for (int e=lane;e<100;e+=64) ws_stage[idx*100 + e] = R[e];
    }
  }
}

// ---- Kernel A2: UL products, VT fold, and WU_b[n] = W_n * UL_b fusion -----
__global__ __launch_bounds__(512)
void fuse_kernel(float* __restrict__ wsf){
  __shared__ cxf ulraw[8][100];          // raw UL[f] = D*S, [i*10+j]
  const int tid = threadIdx.x, wv = tid>>6, lane = tid&63;
  const cxf* stage = (const cxf*)(wsf + 6600);
  cxf* ws_UL = (cxf*)(wsf + 5000);
  cxf* ws_WU = (cxf*)(wsf + 9800);
  const float* V  = wsf;
  const float* Wt = wsf + 200;
  const cxf* Sm = stage + wv*100;
  const cxf* Dm = stage + (8+wv)*100;
  for (int e=lane; e<100; e+=64){
    int i=e/10, j=e-10*i;
    float ax=0.f, ay=0.f;
    for (int k=0;k<10;k++){
      cxf d=Dm[i*10+k], s=Sm[k*10+j];
      ax += d.x*s.x - d.y*s.y;
      ay += d.x*s.y + d.y*s.x;
    }
    ulraw[wv][e] = {ax, ay};
  }
  __syncthreads();
  // f=0 only: UL0 <- V^T * UL0 (carries L1's V0^T). Two elems per lane.
  cxf t0={0.f,0.f}, t1={0.f,0.f};
  if (wv == 0){
    {
      int e=lane, i=e/10, j=e-10*i;
      float ox=0.f, oy=0.f;
      for (int k=0;k<10;k++){ float v=V[k*10+i]; ox+=v*ulraw[0][k*10+j].x; oy+=v*ulraw[0][k*10+j].y; }
      t0 = {ox, oy};
    }
    if (lane+64 < 100){
      int e=lane+64, i=e/10, j=e-10*i;
      float ox=0.f, oy=0.f;
      for (int k=0;k<10;k++){ float v=V[k*10+i]; ox+=v*ulraw[0][k*10+j].x; oy+=v*ulraw[0][k*10+j].y; }
      t1 = {ox, oy};
    }
  }
  __syncthreads();
  if (wv == 0){
    ulraw[0][lane] = t0;
    if (lane+64 < 100) ulraw[0][lane+64] = t1;
  }
  __syncthreads();
  // Export ULt (transposed) for f in {0,4,5,6}
  for (int e=tid; e<400; e+=512){
    int fi = e/100, r = e-100*fi;
    int f = (fi==0) ? 0 : (3+fi);        // 0,4,5,6
    int i=r/10, j=r-10*i;
    ws_UL[f*100 + j*10 + i] = ulraw[f][i*10+j];
  }
  // Phase 2: WU_b[n] = W_n * ulraw[b], id=(b-1)*10+n, 30 tasks over 8 waves.
  for (int round=0; round<4; ++round){
    int id = round*8 + wv;
    if (id < 30){
      int b = 1 + id/10, n = id - (id/10)*10;
      const cxf* Ub = ulraw[b];
      for (int e=lane; e<100; e+=64){
        int i=e/10, j=e-10*i;
        float ax=0.f, ay=0.f;
        for (int k=0;k<10;k++){
          float w = Wt[n*100 + k*10 + i];   // W_n[i][k]
          ax += w*Ub[k*10+j].x;
          ay += w*Ub[k*10+j].y;
        }
        cxf o; o.x=ax; o.y=ay;
        ws_WU[id*100 + j*10 + i] = o;       // transposed
      }
    }
  }
}

// ------------- Kernel B: per-(b,w) encoding vector u = D*(S*e0), fp32 ------
__global__ __launch_bounds__(128)
void enc_kernel(const float* __restrict__ jets, const float* __restrict__ sscale,
                float* __restrict__ wsf){
  __shared__ float scr[2][4][200];
  __shared__ cxf col[10];
  __shared__ cxf uacc[10];
  const int tid = threadIdx.x, wv = tid>>6, lane = tid&63;
  const int blk = blockIdx.x, b = blk>>2, w = blk&3;

  float eta = jets[b*12 + w*3 + 0];
  float jph = jets[b*12 + w*3 + 1];
  float pt  = jets[b*12 + w*3 + 2];

  cxf* M = (cxf*)scr[wv][0];
  cxf* P = (cxf*)scr[wv][1];
  cxf* T = (cxf*)scr[wv][2];
  cxf* R = (cxf*)scr[wv][3];
  {
    float zr, zi;
    if (wv == 0){ float phs = pt*jph*0.5f; zr = eta*cosf(phs); zi = eta*sinf(phs); }
    else {
      double sc = 10.0/(1.0 + exp(-(double)sscale[0])) + 0.01;
      float mag = (float)sc*pt; zr = mag*cosf(eta); zi = mag*sinf(eta);
    }
    for (int e=lane; e<100; e+=64){
      int i=e/10, j=e-10*i;
      M[e] = wv ? gen_disp_f(i,j,zr,zi) : gen_squeeze_f(i,j,zr,zi);
    }
  }
  __syncthreads();
  expm_f32(true, 10, M, P, T, R, lane);
  cxf* Rs = (cxf*)scr[0][3];
  cxf* Rd = (cxf*)scr[1][3];
  if (tid < 10) col[tid] = Rs[tid*10];           // squeeze column 0
  __syncthreads();
  if (tid < 10){
    float ax=0.f, ay=0.f;
    for (int k=0;k<10;k++){
      cxf d = Rd[tid*10+k], c = col[k];
      ax += d.x*c.x - d.y*c.y;
      ay += d.x*c.y + d.y*c.x;
    }
    uacc[tid] = {ax, ay};
  }
  __syncthreads();
  if (tid < 10){
    float rx, ry;
    if (w == 0){
      rx = 0.f; ry = 0.f;
      for (int k=0;k<10;k++){
        float v = wsf[k*10 + tid];               // (V^T)[tid][k]
        rx += v*uacc[k].x;
        ry += v*uacc[k].y;
      }
    } else { rx = uacc[tid].x; ry = uacc[tid].y; }
    float* u_out = wsf + U_OFF + (b*40 + w*10 + tid)*2;
    u_out[0] = rx;
    u_out[1] = ry;
  }
}

// ---------------- Kernel C: the circuit, 2 states/block, v4f LDS -----------
// Padded digit strides: element (c0,c1,c2,c3) -> c0*1010 + c1*101 + c2*10 + c3.
__device__ __forceinline__ constexpr int WS(int w){
  return w==0 ? 1010 : (w==1 ? 101 : (w==2 ? 10 : 1));
}

#define DECLP(P) v4f P##0={0.f,0.f,0.f,0.f}, P##1=P##0, P##2=P##0, P##3=P##0, \
  P##4=P##0, P##5=P##0, P##6=P##0, P##7=P##0, P##8=P##0, P##9=P##0;

#define REX(O,i,u) O##i = __builtin_elementwise_fma((v4f){(u),(u),(u),(u)}, vv, O##i);

#define RPAIRX(O, va, vb, Mp_) { \
  const v4f* Mp = (Mp_); \
  v4f q0=Mp[0],q1=Mp[1],q2=Mp[2],q3=Mp[3],q4=Mp[4]; \
  { v4f vv=va; REX(O,0,q0.x) REX(O,1,q0.y) REX(O,2,q0.z) REX(O,3,q0.w) REX(O,4,q1.x) \
               REX(O,5,q1.y) REX(O,6,q1.z) REX(O,7,q1.w) REX(O,8,q2.x) REX(O,9,q2.y) } \
  { v4f vv=vb; REX(O,0,q2.z) REX(O,1,q2.w) REX(O,2,q3.x) REX(O,3,q3.y) REX(O,4,q3.z) \
               REX(O,5,q3.w) REX(O,6,q4.x) REX(O,7,q4.y) REX(O,8,q4.z) REX(O,9,q4.w) } }

#define RSTAGE(Mt, I, O) \
  RPAIRX(O, I##0, I##1, (const v4f*)((Mt)+0))  \
  RPAIRX(O, I##2, I##3, (const v4f*)((Mt)+20)) \
  RPAIRX(O, I##4, I##5, (const v4f*)((Mt)+40)) \
  RPAIRX(O, I##6, I##7, (const v4f*)((Mt)+60)) \
  RPAIRX(O, I##8, I##9, (const v4f*)((Mt)+80))

#define CEX(O,i,ur,ui) \
  O##i = __builtin_elementwise_fma((v4f){(ur),(ur),(ur),(ur)}, vv, O##i); \
  O##i = __builtin_elementwise_fma((v4f){-(ui),(ui),-(ui),(ui)}, vs, O##i);

#define CROWX(O, vk, Up_) { \
  const v4f* Up = (Up_); \
  v4f q0=Up[0],q1=Up[1],q2=Up[2],q3=Up[3],q4=Up[4]; \
  v4f vv=vk, vs=__builtin_shufflevector(vk,vk,1,0,3,2); \
  CEX(O,0,q0.x,q0.y) CEX(O,1,q0.z,q0.w) CEX(O,2,q1.x,q1.y) CEX(O,3,q1.z,q1.w) \
  CEX(O,4,q2.x,q2.y) CEX(O,5,q2.z,q2.w) CEX(O,6,q3.x,q3.y) CEX(O,7,q3.z,q3.w) \
  CEX(O,8,q4.x,q4.y) CEX(O,9,q4.z,q4.w) }

// measure variant: output row 0 (photon number 0, weight 0) skipped.
#define CROWX9(O, vk, Up_) { \
  const v4f* Up = (Up_); \
  v4f q0=Up[0],q1=Up[1],q2=Up[2],q3=Up[3],q4=Up[4]; \
  v4f vv=vk, vs=__builtin_shufflevector(vk,vk,1,0,3,2); \
  CEX(O,1,q0.z,q0.w) CEX(O,2,q1.x,q1.y) CEX(O,3,q1.z,q1.w) \
  CEX(O,4,q2.x,q2.y) CEX(O,5,q2.z,q2.w) CEX(O,6,q3.x,q3.y) CEX(O,7,q3.z,q3.w) \
  CEX(O,8,q4.x,q4.y) CEX(O,9,q4.z,q4.w) }

#define CSTAGE(U, I, O) \
  CROWX(O, I##0, (const v4f*)((U)+0))  CROWX(O, I##1, (const v4f*)((U)+10)) \
  CROWX(O, I##2, (const v4f*)((U)+20)) CROWX(O, I##3, (const v4f*)((U)+30)) \
  CROWX(O, I##4, (const v4f*)((U)+40)) CROWX(O, I##5, (const v4f*)((U)+50)) \
  CROWX(O, I##6, (const v4f*)((U)+60)) CROWX(O, I##7, (const v4f*)((U)+70)) \
  CROWX(O, I##8, (const v4f*)((U)+80)) CROWX(O, I##9, (const v4f*)((U)+90))

#define CSTAGE9(U, I, O) \
  CROWX9(O, I##0, (const v4f*)((U)+0))  CROWX9(O, I##1, (const v4f*)((U)+10)) \
  CROWX9(O, I##2, (const v4f*)((U)+20)) CROWX9(O, I##3, (const v4f*)((U)+30)) \
  CROWX9(O, I##4, (const v4f*)((U)+40)) CROWX9(O, I##5, (const v4f*)((U)+50)) \
  CROWX9(O, I##6, (const v4f*)((U)+60)) CROWX9(O, I##7, (const v4f*)((U)+70)) \
  CROWX9(O, I##8, (const v4f*)((U)+80)) CROWX9(O, I##9, (const v4f*)((U)+90))

#define LDS_RD10 \
  v4f r0=S[base], r1=S[base+sm], r2=S[base+2*sm], r3=S[base+3*sm], r4=S[base+4*sm], \
      r5=S[base+5*sm], r6=S[base+6*sm], r7=S[base+7*sm], r8=S[base+8*sm], r9=S[base+9*sm];

#define PSTORE10(P) { S[base]=P##0; S[base+sm]=P##1; S[base+2*sm]=P##2; S[base+3*sm]=P##3; \
  S[base+4*sm]=P##4; S[base+5*sm]=P##5; S[base+6*sm]=P##6; S[base+7*sm]=P##7; \
  S[base+8*sm]=P##8; S[base+9*sm]=P##9; }

// ---- wave-uniform conditional passes --------------------------------------
// Task t in [0,20): cond digit n = t>>1 (wave-uniform), half = t&1.
// 50 lanes handle fibers f = half*50 + lane over spectators (qa,qb).
__device__ __forceinline__ void do_Wtask(v4f* S, const float* __restrict__ Wall,
                                         int sc, int sm, int sa, int sb,
                                         int t, int lane){
  int n = t>>1, half = t&1;
  if (lane < 50){
    int f = half*50 + lane;
    int qa = f/10, qb = f - 10*qa;
    int base = n*sc + qa*sa + qb*sb;
    const float* __restrict__ Mt = Wall + n*100;   // n uniform -> s_load
    LDS_RD10
    DECLP(a) RSTAGE(Mt, r, a)
    PSTORE10(a)
  }
}
__device__ __forceinline__ void applyW_u(v4f* S, const float* __restrict__ Wall,
                                         int sc, int sm, int sa, int sb,
                                         int wid, int lane){
  do_Wtask(S, Wall, sc, sm, sa, sb, wid, lane);
  if (wid < 4) do_Wtask(S, Wall, sc, sm, sa, sb, 16+wid, lane);
}

__device__ __forceinline__ void do_WUtask(v4f* S, const cxf* __restrict__ WUb,
                                          int sc, int sm, int sa, int sb,
                                          int t, int lane){
  int n = t>>1, half = t&1;
  if (lane < 50){
    int f = half*50 + lane;
    int qa = f/10, qb = f - 10*qa;
    int base = n*sc + qa*sa + qb*sb;
    const cxf* __restrict__ U = WUb + n*100;       // n uniform -> s_load
    LDS_RD10
    DECLP(a) CSTAGE(U, r, a)
    PSTORE10(a)
  }
}
__device__ __forceinline__ void applyWU_u(v4f* S, const cxf* __restrict__ WUb,
                                          int sc, int sm, int sa, int sb,
                                          int wid, int lane){
  do_WUtask(S, WUb, sc, sm, sa, sb, wid, lane);
  if (wid < 4) do_WUtask(S, WUb, sc, sm, sa, sb, 16+wid, lane);
}

// BS task t in [0,38): bn = t>>1 (wave-uniform -> uniform sz loop), half = t&1.
__device__ __forceinline__ void do_BStask(v4f* S, const cxf* __restrict__ BSp,
                                          int sa, int sb, int s1, int s2, int ds,
                                          int t, int lane){
  int bn = t>>1, half = t&1;
  int ilo = bn<10?0:bn-9, ihi = bn<10?bn:9, sz = ihi-ilo+1;
  if (lane < 50){
    int f = half*50 + lane;
    int ca = f/10, cb = f - 10*ca;
    int base = ca*sa + cb*sb;
    const cxf* __restrict__ Bt = BSp + bn*100;     // bn uniform -> s_load
    DECLP(a)
    int radr = base + ilo*s1 + (bn-ilo)*s2;
    int kk = 0;
    #pragma unroll 1
    for (int c=0;c<sz;c++){
      v4f rk = S[radr];
      CROWX(a, rk, (const v4f*)(Bt + kk))
      radr += ds; kk += 10;
    }
    int wadr = base + ilo*s1 + (bn-ilo)*s2;
    #define BSTQ(r) if ((r) < sz){ S[wadr] = a##r; wadr += ds; }
    BSTQ(0) BSTQ(1) BSTQ(2) BSTQ(3) BSTQ(4) BSTQ(5) BSTQ(6) BSTQ(7) BSTQ(8) BSTQ(9)
    #undef BSTQ
  }
}
__device__ __forceinline__ void applyBS_u(v4f* S, const cxf* __restrict__ BSp,
                                          int sa, int sb, int s1, int s2,
                                          int wid, int lane){
  const int ds = s1 - s2;
  do_BStask(S, BSp, sa, sb, s1, s2, ds, wid, lane);
  do_BStask(S, BSp, sa, sb, s1, s2, ds, wid+16, lane);
  if (wid < 6) do_BStask(S, BSp, sa, sb, s1, s2, ds, wid+32, lane);
}

// ---- uniform single-wire passes (full 1024-thread map) --------------------
__device__ __forceinline__ void apply1_r4(v4f* S, const float* __restrict__ Mt, int m, int tid){
  const int sm = WS(m);
  const int x0 = (m==0)?1:0, x1=(m<=1)?2:1, x2=(m<=2)?3:2;
  const int s0 = WS(x0), s1 = WS(x1), s2 = WS(x2);
  if (tid < 1000){
    int d0=tid/100, rem=tid-100*d0, d1=rem/10, d2=rem-10*d1;
    int base = d0*s0 + d1*s1 + d2*s2;
    LDS_RD10
    DECLP(a) RSTAGE(Mt, r, a)
    PSTORE10(a)
  }
}

__device__ __forceinline__ void apply1_c4(v4f* S, const cxf* __restrict__ U, int m, int tid){
  const int sm = WS(m);
  const int x0 = (m==0)?1:0, x1=(m<=1)?2:1, x2=(m<=2)?3:2;
  const int s0 = WS(x0), s1 = WS(x1), s2 = WS(x2);
  if (tid < 1000){
    int d0=tid/100, rem=tid-100*d0, d1=rem/10, d2=rem-10*d1;
    int base = d0*s0 + d1*s1 + d2*s2;
    LDS_RD10
    DECLP(a) CSTAGE(U, r, a)
    PSTORE10(a)
  }
}

// Read-only measure: per-state sum_i i*|(U v)_i|^2; output row 0 skipped.
__device__ __forceinline__ v2f measure14(const v4f* S, const cxf* __restrict__ U, int m, int tid){
  const int sm = WS(m);
  const int x0 = (m==0)?1:0, x1=(m<=1)?2:1, x2=3;
  const int s0 = WS(x0), s1 = WS(x1), s2 = WS(x2);
  v2f s = {0.f, 0.f};
  if (tid < 1000){
    int d0=tid/100, rem=tid-100*d0, d1=rem/10, d2=rem-10*d1;
    int base = d0*s0 + d1*s1 + d2*s2;
    LDS_RD10
    DECLP(a) CSTAGE9(U, r, a)
    #define MQ4(i) { s.x += (float)(i)*(a##i.x*a##i.x + a##i.y*a##i.y); \
                     s.y += (float)(i)*(a##i.z*a##i.z + a##i.w*a##i.w); }
    MQ4(1) MQ4(2) MQ4(3) MQ4(4) MQ4(5) MQ4(6) MQ4(7) MQ4(8) MQ4(9)
    #undef MQ4
  }
  return s;
}

__global__ __launch_bounds__(NTB)
__attribute__((amdgpu_waves_per_eu(4)))
void state_kernel(const float* __restrict__ wd, const float* __restrict__ bd,
                  const float* __restrict__ wsf, float* __restrict__ out){
  extern __shared__ __align__(16) char smem[];
  v4f* S    = (v4f*)smem;                  // 10099 v4f (161584 B)
  cxf* uv   = (cxf*)(smem + 161584);       // 2 states * 4*10 encoding vectors
  v2f* red  = (v2f*)(smem + 162224);       // 16 waves

  const float* __restrict__ V   = wsf;            // for V^T gate
  const float* __restrict__ VT  = wsf + 100;      // for V gate
  const float* __restrict__ W   = wsf + 200;
  const cxf*   __restrict__ BSm = (const cxf*)(wsf + 1200);
  const cxf*   __restrict__ UL  = (const cxf*)(wsf + 5000);
  const cxf*   __restrict__ WU  = (const cxf*)(wsf + 9800);
  const cxf*   __restrict__ uw  = (const cxf*)(wsf + U_OFF);

  const int tid = threadIdx.x, wv = tid>>6, lane = tid&63;
  const int wid = __builtin_amdgcn_readfirstlane(tid) >> 6;  // scalar wave id
  const int b = blockIdx.x;                // batch items 2b, 2b+1

  if (tid < 80) uv[tid] = uw[b*80 + tid];
  __syncthreads();

  // Init: both product states, interleaved {re0,im0,re1,im1}.
  for (int e=tid; e<10000; e+=NTB){
    int c0=e/1000, r_=e-1000*c0, c1=r_/100, r2_=r_-100*c1, c2=r2_/10, c3=r2_-10*c2;
    cxf A0 = uv[c0],    B0 = uv[10+c1], C0 = uv[20+c2], D0 = uv[30+c3];
    cxf A1 = uv[40+c0], B1 = uv[50+c1], C1 = uv[60+c2], D1 = uv[70+c3];
    float pr = A0.x*B0.x - A0.y*B0.y, pi = A0.x*B0.y + A0.y*B0.x;
    float qr = pr*C0.x - pi*C0.y,  qi = pr*C0.y + pi*C0.x;
    float e0r = qr*D0.x - qi*D0.y, e0i = qr*D0.y + qi*D0.x;
    pr = A1.x*B1.x - A1.y*B1.y; pi = A1.x*B1.y + A1.y*B1.x;
    qr = pr*C1.x - pi*C1.y;  qi = pr*C1.y + pi*C1.x;
    float e1r = qr*D1.x - qi*D1.y, e1i = qr*D1.y + qi*D1.x;
    S[c0*1010 + c1*101 + c2*10 + c3] = (v4f){e0r, e0i, e1r, e1i};
  }
  __syncthreads();

  // ---------------- Layer 0 (R21 order, wave-uniform conditionals) --------
  applyW_u(S, W, 1010, 101, 10, 1, wid, lane); __syncthreads();    // W(0,1)
  applyW_u(S, W, 1010, 10, 101, 1, wid, lane); __syncthreads();    // W(0,2)
  applyW_u(S, W, 1010, 1, 10, 101, wid, lane); __syncthreads();    // W(0,3) swap
  apply1_r4(S, VT, 0, tid); __syncthreads();      // V0
  apply1_r4(S, V, 1, tid);  __syncthreads();      // V1^T
  applyW_u(S, W, 101, 10, 1010, 1, wid, lane); __syncthreads();    // W(1,2)
  applyW_u(S, W, 101, 1, 1010, 10, wid, lane); __syncthreads();    // W(1,3)
  apply1_r4(S, VT, 1, tid); __syncthreads();      // V1
  apply1_r4(S, V, 2, tid);  __syncthreads();      // V2^T
  applyW_u(S, W, 10, 1, 1010, 101, wid, lane); __syncthreads();    // W(2,3)
  apply1_r4(S, VT, 2, tid); __syncthreads();      // V2
  applyBS_u(S, BSm, 10, 1, 1010, 101, wid, lane); __syncthreads(); // BS(0,1)
  applyBS_u(S, BSm, 1010, 1, 101, 10, wid, lane); __syncthreads(); // BS(1,2)
  applyBS_u(S, BSm, 1010, 101, 10, 1, wid, lane); __syncthreads(); // BS(2,3)
  applyBS_u(S, BSm, 10, 101, 1, 1010, wid, lane); __syncthreads(); // BS(3,0) swap
  apply1_c4(S, UL, 0, tid); __syncthreads();      // UL0_L0 (carries L1's V0^T)

  // ---------------- Layer 1 ----------------
  applyWU_u(S, WU,        1010, 101, 10, 1, wid, lane); __syncthreads(); // WU(1)
  applyWU_u(S, WU + 1000, 1010, 10, 101, 1, wid, lane); __syncthreads(); // WU(2)
  applyWU_u(S, WU + 2000, 1010, 1, 10, 101, wid, lane); __syncthreads(); // WU(3) swap
  apply1_r4(S, VT, 0, tid); __syncthreads();      // V0
  apply1_r4(S, V, 1, tid);  __syncthreads();      // V1^T
  applyW_u(S, W, 101, 10, 1010, 1, wid, lane); __syncthreads();    // W(1,2)
  applyW_u(S, W, 101, 1, 1010, 10, wid, lane); __syncthreads();    // W(1,3)
  apply1_r4(S, VT, 1, tid); __syncthreads();      // V1
  apply1_r4(S, V, 2, tid);  __syncthreads();      // V2^T
  applyW_u(S, W, 10, 1, 1010, 101, wid, lane); __syncthreads();    // W(2,3)
  apply1_r4(S, VT, 2, tid); __syncthreads();      // V2
  applyBS_u(S, BSm, 10, 1, 1010, 101, wid, lane); __syncthreads(); // BS(0,1)
  applyBS_u(S, BSm, 1010, 1, 101, 10, wid, lane); __syncthreads(); // BS(1,2)
  applyBS_u(S, BSm, 1010, 101, 10, 1, wid, lane); __syncthreads(); // BS(2,3)
  applyBS_u(S, BSm, 10, 101, 1, 1010, wid, lane); __syncthreads(); // BS(3,0)

  // Fused measurement: UL[L1,m] applied read-only; UL[L1,3] dropped.
  float w0 = wd[0], w1 = wd[1], w2 = wd[2];
  v2f m0 = measure14(S, UL + 400, 0, tid);
  v2f m1 = measure14(S, UL + 500, 1, tid);
  v2f m2 = measure14(S, UL + 600, 2, tid);
  v2f acc;
  acc.x = w0*m0.x + w1*m1.x + w2*m2.x;
  acc.y = w0*m0.y + w1*m1.y + w2*m2.y;

  for (int off=32; off; off>>=1){
    acc.x += __shfl_down(acc.x, off, 64);
    acc.y += __shfl_down(acc.y, off, 64);
  }
  if (lane == 0) red[wv] = acc;
  __syncthreads();
  if (tid == 0){
    float sx = 0.f, sy = 0.f;
    for (int i=0;i<16;i++){ sx += red[i].x; sy += red[i].y; }
    out[2*b+0] = sx + bd[0];
    out[2*b+1] = sy + bd[0];
  }
}

} // anonymous namespace

extern "C" void kernel_launch(void* const* d_in, const int* in_sizes, int n_in,
                              void* d_out, int out_size, void* d_ws, size_t ws_size,
                              hipStream_t stream){
  const float* jets   = (const float*)d_in[0];
  const float* sscale = (const float*)d_in[1];
  const float* dmag   = (const float*)d_in[2];
  const float* dphase = (const float*)d_in[3];
  const float* smag   = (const float*)d_in[4];
  const float* sphase = (const float*)d_in[5];
  const float* wd     = (const float*)d_in[6];
  const float* bd     = (const float*)d_in[7];
  float* out = (float*)d_out;
  float* wsf = (float*)d_ws;
  int B = in_sizes[0] / 12;

  (void)hipFuncSetAttribute(reinterpret_cast<const void*>(&state_kernel),
                            hipFuncAttributeMaxDynamicSharedMemorySize, SMEM_STATE);

  gates_kernel<<<12, 256, 0, stream>>>(dmag, dphase, smag, sphase, wsf);
  fuse_kernel<<<1, 512, 0, stream>>>(wsf);
  enc_kernel<<<B*4, 128, 0, stream>>>(jets, sscale, wsf);
  state_kernel<<<B/2, NTB, SMEM_STATE, stream>>>(wd, bd, wsf, out);
}